// Round 13
// baseline (1260.871 us; speedup 1.0000x reference)
//
#include <hip/hip_runtime.h>
#include <math.h>

#define BB   8
#define SS   1024
#define EE   512
#define HH   8
#define DHH  64
#define LLY  2
#define CC   8921
#define CP   9088          // C padded to multiple of 128
#define DFF_ 2048

typedef short          bf16x8 __attribute__((ext_vector_type(8)));
typedef float          f32x4  __attribute__((ext_vector_type(4)));
typedef unsigned short u16x4  __attribute__((ext_vector_type(4)));
typedef unsigned short u16x8  __attribute__((ext_vector_type(8)));

__device__ __forceinline__ float bf2f(unsigned short u) {
    return __uint_as_float(((unsigned int)u) << 16);
}
__device__ __forceinline__ unsigned short f2bf(float f) {
    unsigned int u = __float_as_uint(f);
    u = (u + 0x7FFFu + ((u >> 16) & 1u)) >> 16;
    return (unsigned short)u;
}
__device__ __forceinline__ void gload16(const void* g, void* l) {
    __builtin_amdgcn_global_load_lds(
        (const __attribute__((address_space(1))) void*)g,
        (__attribute__((address_space(3))) void*)l, 16, 0, 0);
}

// ---------------------------------------------------------------------------
// f32 -> bf16 convert with zero-pad
// ---------------------------------------------------------------------------
__global__ __launch_bounds__(256) void cvt_bf16(const float* __restrict__ in,
                                                unsigned short* __restrict__ out,
                                                long n_in, long n_out)
{
    const long i4 = ((long)blockIdx.x * 256 + threadIdx.x) * 4;
    if (i4 >= n_out) return;
    u16x4 r;
    if (i4 < n_in) {
        const float4 v = *(const float4*)(in + i4);
        r[0] = f2bf(v.x); r[1] = f2bf(v.y); r[2] = f2bf(v.z); r[3] = f2bf(v.w);
    } else {
        r[0] = r[1] = r[2] = r[3] = 0;
    }
    *(u16x4*)(out + i4) = r;
}

// ---------------------------------------------------------------------------
// embed: x = inputs*sqrt(E) + pe[b]  (pe indexed by batch — source bug kept)
// ---------------------------------------------------------------------------
__global__ __launch_bounds__(256) void embed_kernel(const float* __restrict__ in,
                                                    const float* __restrict__ pe,
                                                    float* __restrict__ x,
                                                    unsigned short* __restrict__ xb)
{
    const long i  = (long)blockIdx.x * 256 + threadIdx.x;
    const int  e4 = (int)(i & 127);
    const int  b  = (int)(i >> 17);
    float4 v = ((const float4*)in)[i];
    const float4 p = ((const float4*)pe)[b * 128 + e4];
    const float sc = 22.627416997969522f;
    v.x = v.x * sc + p.x;  v.y = v.y * sc + p.y;
    v.z = v.z * sc + p.z;  v.w = v.w * sc + p.w;
    ((float4*)x)[i] = v;
    u16x4 h; h[0] = f2bf(v.x); h[1] = f2bf(v.y); h[2] = f2bf(v.z); h[3] = f2bf(v.w);
    ((u16x4*)xb)[i] = h;
}

// ---------------------------------------------------------------------------
// bf16 MFMA GEMM, tile 128 x (32*FN), BK=64. FN=4: 128x128; FN=2: 128x64.
// ---------------------------------------------------------------------------
template<int FN>
__global__ __launch_bounds__(256) void gemm_mfma_t(const unsigned short* __restrict__ A,
                                                   const unsigned short* __restrict__ B,
                                                   const float* __restrict__ bias,
                                                   float* __restrict__ Cf,
                                                   unsigned short* __restrict__ Ch,
                                                   int M, int N, int K, int Mlim,
                                                   long sAz, long sBz, long sCz,
                                                   int act, int mode)
{
    __shared__ unsigned short As[128 * 64];
    __shared__ unsigned short Bs[32 * FN * 64];
    const int t  = threadIdx.x;
    const int wv = t >> 6, ln = t & 63;
    const int wr = wv >> 1, wc = wv & 1;
    const int lr = ln & 15, lg = ln >> 4;
    const int m0 = blockIdx.x * 128, n0 = blockIdx.y * (32 * FN);
    const int z  = blockIdx.z;
    const unsigned short* Ab = A + (long)z * sAz;
    const unsigned short* Bb = B + (long)z * sBz;

    const int srow = ln >> 3;
    const int ucol = ((ln & 7) ^ srow) << 3;

    f32x4 acc[4][FN];
    #pragma unroll
    for (int i = 0; i < 4; ++i)
        #pragma unroll
        for (int j = 0; j < FN; ++j)
            acc[i][j] = (f32x4){0.f, 0.f, 0.f, 0.f};

    int rA[4], rB[FN];
    #pragma unroll
    for (int f = 0; f < 4; ++f) rA[f] = wr * 64 + f * 16 + lr;
    #pragma unroll
    for (int f = 0; f < FN; ++f) rB[f] = wc * (16 * FN) + f * 16 + lr;

    for (int k0 = 0; k0 < K; k0 += 64) {
        __syncthreads();
        #pragma unroll
        for (int c = 0; c < 4; ++c) {
            const int q   = (wv << 2) + c;
            const int row = (q << 3) + srow;
            gload16(Ab + (long)(m0 + row) * K + k0 + ucol, (char*)As + (q << 10));
        }
        #pragma unroll
        for (int c = 0; c < FN; ++c) {
            const int q   = wv * FN + c;
            const int row = (q << 3) + srow;
            gload16(Bb + (long)(n0 + row) * K + k0 + ucol, (char*)Bs + (q << 10));
        }
        __syncthreads();
        #pragma unroll
        for (int kk = 0; kk < 2; ++kk) {
            bf16x8 af[4], bg[FN];
            const int s = (kk << 2) + lg;
            #pragma unroll
            for (int f = 0; f < 4; ++f)
                af[f] = *(const bf16x8*)((const char*)As + rA[f] * 128 + ((s ^ (rA[f] & 7)) << 4));
            #pragma unroll
            for (int f = 0; f < FN; ++f)
                bg[f] = *(const bf16x8*)((const char*)Bs + rB[f] * 128 + ((s ^ (rB[f] & 7)) << 4));
            #pragma unroll
            for (int i = 0; i < 4; ++i)
                #pragma unroll
                for (int j = 0; j < FN; ++j)
                    acc[i][j] = __builtin_amdgcn_mfma_f32_16x16x32_bf16(af[i], bg[j], acc[i][j], 0, 0, 0);
        }
    }

    const long zC = (long)z * sCz;
    #pragma unroll
    for (int fm = 0; fm < 4; ++fm) {
        #pragma unroll
        for (int reg = 0; reg < 4; ++reg) {
            const int gm = m0 + wr * 64 + fm * 16 + lg * 4 + reg;
            if (gm >= Mlim) continue;
            #pragma unroll
            for (int fn = 0; fn < FN; ++fn) {
                const int gn = n0 + wc * (16 * FN) + fn * 16 + lr;
                float v = acc[fm][fn][reg];
                if (bias) v += bias[gn];
                if (act == 1)      v = fmaxf(v, 0.f);
                else if (act == 2) v = tanhf(v);
                if (mode & 1) Cf[zC + (long)gm * N + gn] = v;
                if (mode & 2) Ch[zC + (long)gm * N + gn] = f2bf(v);
            }
        }
    }
}

// ---------------------------------------------------------------------------
// XCD-aware bijective block remap for the scores GEMM (4544 = 8 x 568).
// ---------------------------------------------------------------------------
__device__ __forceinline__ void label_swizzle(int& bx, int& by, int& bz)
{
    const int flat = blockIdx.x + 71 * (blockIdx.y + 8 * blockIdx.z);
    const int swz  = (flat & 7) * 568 + (flat >> 3);
    bx = swz >> 6;            // [0,71)
    by = swz & 7;
    bz = (swz >> 3) & 7;
}

// ---------------------------------------------------------------------------
// Label scores GEMM + per-row-slice softmax stats.
// BF16RAW: raw -> rawb (bf16);  else raw -> attnW (f32, in-place path).
// ---------------------------------------------------------------------------
template<bool BF16RAW>
__global__ __launch_bounds__(256) void gemm_scores_t(const unsigned short* __restrict__ A,   // labelb [CP,E]
                                                     const unsigned short* __restrict__ B,   // o1b [B*S,E]
                                                     float* __restrict__ attnW,              // [B,CC,S]
                                                     unsigned short* __restrict__ rawb,      // [B,CC,S] bf16
                                                     float2* __restrict__ stats)             // [B,CP,16]
{
    __shared__ unsigned short As[128 * 64];
    __shared__ unsigned short Bs[128 * 64];
    int bx, by, bz;
    label_swizzle(bx, by, bz);
    const int t  = threadIdx.x;
    const int wv = t >> 6, ln = t & 63;
    const int wr = wv >> 1, wc = wv & 1;
    const int lr = ln & 15, lg = ln >> 4;
    const int m0 = bx * 128, n0 = by * 128;
    const int z  = bz;
    const unsigned short* Bb = B + (long)z * SS * EE;

    const int srow = ln >> 3;
    const int ucol = ((ln & 7) ^ srow) << 3;

    f32x4 acc[4][4];
    #pragma unroll
    for (int i = 0; i < 4; ++i)
        #pragma unroll
        for (int j = 0; j < 4; ++j)
            acc[i][j] = (f32x4){0.f, 0.f, 0.f, 0.f};

    int rA[4], rB[4];
    #pragma unroll
    for (int f = 0; f < 4; ++f) {
        rA[f] = wr * 64 + f * 16 + lr;
        rB[f] = wc * 64 + f * 16 + lr;
    }

    for (int k0 = 0; k0 < EE; k0 += 64) {
        __syncthreads();
        #pragma unroll
        for (int c = 0; c < 4; ++c) {
            const int q   = (wv << 2) + c;
            const int row = (q << 3) + srow;
            gload16(A  + (long)(m0 + row) * EE + k0 + ucol, (char*)As + (q << 10));
            gload16(Bb + (long)(n0 + row) * EE + k0 + ucol, (char*)Bs + (q << 10));
        }
        __syncthreads();
        #pragma unroll
        for (int kk = 0; kk < 2; ++kk) {
            bf16x8 af[4], bg[4];
            const int s = (kk << 2) + lg;
            #pragma unroll
            for (int f = 0; f < 4; ++f) {
                af[f] = *(const bf16x8*)((const char*)As + rA[f] * 128 + ((s ^ (rA[f] & 7)) << 4));
                bg[f] = *(const bf16x8*)((const char*)Bs + rB[f] * 128 + ((s ^ (rB[f] & 7)) << 4));
            }
            #pragma unroll
            for (int i = 0; i < 4; ++i)
                #pragma unroll
                for (int j = 0; j < 4; ++j)
                    acc[i][j] = __builtin_amdgcn_mfma_f32_16x16x32_bf16(af[i], bg[j], acc[i][j], 0, 0, 0);
        }
    }

    float* aw = attnW + (long)z * CC * SS;
    unsigned short* rb = rawb + (long)z * CC * SS;
    #pragma unroll
    for (int fm = 0; fm < 4; ++fm) {
        #pragma unroll
        for (int reg = 0; reg < 4; ++reg) {
            const int r = m0 + wr * 64 + fm * 16 + lg * 4 + reg;
            const float v0 = acc[fm][0][reg], v1 = acc[fm][1][reg];
            const float v2 = acc[fm][2][reg], v3 = acc[fm][3][reg];
            if (r < CC) {
                #pragma unroll
                for (int fn = 0; fn < 4; ++fn) {
                    const int sn = n0 + wc * 64 + fn * 16 + lr;
                    if (BF16RAW) rb[(long)r * SS + sn] = f2bf(acc[fm][fn][reg]);
                    else         aw[(long)r * SS + sn] = acc[fm][fn][reg];
                }
            }
            float mx = fmaxf(fmaxf(v0, v1), fmaxf(v2, v3));
            mx = fmaxf(mx, __shfl_xor(mx, 1));
            mx = fmaxf(mx, __shfl_xor(mx, 2));
            mx = fmaxf(mx, __shfl_xor(mx, 4));
            mx = fmaxf(mx, __shfl_xor(mx, 8));
            float sm = __expf(v0 - mx) + __expf(v1 - mx) + __expf(v2 - mx) + __expf(v3 - mx);
            sm += __shfl_xor(sm, 1); sm += __shfl_xor(sm, 2);
            sm += __shfl_xor(sm, 4); sm += __shfl_xor(sm, 8);
            if (lr == 0 && r < CC)
                stats[((long)z * CP + r) * 16 + by * 2 + wc] = make_float2(mx, sm);
        }
    }
}

// ---------------------------------------------------------------------------
// merge 16 slice-stats per row -> (max, 1/sum)
// ---------------------------------------------------------------------------
__global__ __launch_bounds__(256) void merge_stats(const float2* __restrict__ stats,
                                                   float2* __restrict__ rowstat)
{
    const long idx = (long)blockIdx.x * 256 + threadIdx.x;   // z*CP + c
    if (idx >= (long)BB * CP) return;
    const int c = (int)(idx % CP);
    if (c >= CC) return;
    const float2* s = stats + idx * 16;
    float mx = -1e30f;
    #pragma unroll
    for (int i = 0; i < 16; ++i) mx = fmaxf(mx, s[i].x);
    float tot = 0.f;
    #pragma unroll
    for (int i = 0; i < 16; ++i) tot += s[i].y * __expf(s[i].x - mx);
    rowstat[idx] = make_float2(mx, 1.f / tot);
}

// ---------------------------------------------------------------------------
// outputs init: out[b,c] = fc_b[c]
// ---------------------------------------------------------------------------
__global__ __launch_bounds__(256) void init_out(float* __restrict__ out,
                                                const float* __restrict__ fcb)
{
    const int i = blockIdx.x * 256 + threadIdx.x;
    if (i < BB * CC) out[i] = fcb[i % CC];
}

// ---------------------------------------------------------------------------
// Fused final, s-loop version: one block owns 128 c-rows x ALL 1024 s.
// Per s-tile: K-loop D=fcw.x; p=exp(raw-mx)*inv -> f32 p to attnW;
// out partial accumulates lane-locally; end: shuffle-reduce + ONE atomicAdd
// per row per wc-wave (2 total/row; out pre-initialized to fc_b).
// Grid (71,1,8); XCD swizzle: each XCD gets ~9 contiguous A-panels.
// ---------------------------------------------------------------------------
template<bool BF16RAW>
__global__ __launch_bounds__(256) void gemm_label_final_t(const unsigned short* __restrict__ A,  // fcwb [CP,E]
                                                          const unsigned short* __restrict__ B,  // xb [B*S,E]
                                                          float* __restrict__ attnW,             // [B,CC,S] <- p
                                                          const unsigned short* __restrict__ rawb,
                                                          const float2* __restrict__ rowstat,    // [B,CP]
                                                          float* __restrict__ out)               // [B,C]
{
    __shared__ unsigned short As[128 * 64];
    __shared__ unsigned short Bs[128 * 64];
    const int flat = blockIdx.x + 71 * blockIdx.z;
    const int swz  = (flat & 7) * 71 + (flat >> 3);
    const int bx   = swz >> 3;          // 0..70
    const int z    = swz & 7;
    const int t  = threadIdx.x;
    const int wv = t >> 6, ln = t & 63;
    const int wr = wv >> 1, wc = wv & 1;
    const int lr = ln & 15, lg = ln >> 4;
    const int m0 = bx * 128;
    const unsigned short* Bb = B + (long)z * SS * EE;

    const int srow = ln >> 3;
    const int ucol = ((ln & 7) ^ srow) << 3;

    int rA[4], rB[4];
    #pragma unroll
    for (int f = 0; f < 4; ++f) {
        rA[f] = wr * 64 + f * 16 + lr;
        rB[f] = wc * 64 + f * 16 + lr;
    }

    float* aw = attnW + (long)z * CC * SS;
    const unsigned short* rb = rawb + (long)z * CC * SS;
    const float2* rs = rowstat + (long)z * CP;

    float outAcc[4][4];
    #pragma unroll
    for (int i = 0; i < 4; ++i)
        #pragma unroll
        for (int j = 0; j < 4; ++j)
            outAcc[i][j] = 0.f;

    for (int sy = 0; sy < 8; ++sy) {
        const int n0 = sy << 7;
        f32x4 acc[4][4];
        #pragma unroll
        for (int i = 0; i < 4; ++i)
            #pragma unroll
            for (int j = 0; j < 4; ++j)
                acc[i][j] = (f32x4){0.f, 0.f, 0.f, 0.f};

        for (int k0 = 0; k0 < EE; k0 += 64) {
            __syncthreads();
            #pragma unroll
            for (int c = 0; c < 4; ++c) {
                const int q   = (wv << 2) + c;
                const int row = (q << 3) + srow;
                gload16(A  + (long)(m0 + row) * EE + k0 + ucol, (char*)As + (q << 10));
                gload16(Bb + (long)(n0 + row) * EE + k0 + ucol, (char*)Bs + (q << 10));
            }
            __syncthreads();
            #pragma unroll
            for (int kk = 0; kk < 2; ++kk) {
                bf16x8 af[4], bg[4];
                const int s = (kk << 2) + lg;
                #pragma unroll
                for (int f = 0; f < 4; ++f) {
                    af[f] = *(const bf16x8*)((const char*)As + rA[f] * 128 + ((s ^ (rA[f] & 7)) << 4));
                    bg[f] = *(const bf16x8*)((const char*)Bs + rB[f] * 128 + ((s ^ (rB[f] & 7)) << 4));
                }
                #pragma unroll
                for (int i = 0; i < 4; ++i)
                    #pragma unroll
                    for (int j = 0; j < 4; ++j)
                        acc[i][j] = __builtin_amdgcn_mfma_f32_16x16x32_bf16(af[i], bg[j], acc[i][j], 0, 0, 0);
            }
        }

        #pragma unroll
        for (int fm = 0; fm < 4; ++fm) {
            #pragma unroll
            for (int reg = 0; reg < 4; ++reg) {
                const int r = m0 + wr * 64 + fm * 16 + lg * 4 + reg;
                if (r < CC) {
                    const float2 st = rs[r];
                    #pragma unroll
                    for (int fn = 0; fn < 4; ++fn) {
                        const int sn = n0 + wc * 64 + fn * 16 + lr;
                        const float raw = BF16RAW ? bf2f(rb[(long)r * SS + sn])
                                                  : aw[(long)r * SS + sn];
                        const float p = __expf(raw - st.x) * st.y;
                        aw[(long)r * SS + sn] = p;
                        outAcc[fm][reg] += p * acc[fm][fn][reg];
                    }
                }
            }
        }
    }

    float* outb = out + (long)z * CC;
    #pragma unroll
    for (int fm = 0; fm < 4; ++fm) {
        #pragma unroll
        for (int reg = 0; reg < 4; ++reg) {
            const int r = m0 + wr * 64 + fm * 16 + lg * 4 + reg;
            float pacc = outAcc[fm][reg];
            pacc += __shfl_xor(pacc, 1);
            pacc += __shfl_xor(pacc, 2);
            pacc += __shfl_xor(pacc, 4);
            pacc += __shfl_xor(pacc, 8);
            if (lr == 0 && r < CC) atomicAdd(&outb[r], pacc);   // 2 waves (wc=0/1) per row
        }
    }
}

// ---------------------------------------------------------------------------
// V transpose: qkv v-part [b,s,(h,d)] -> Vt [bh, d, s]   (bf16)
// ---------------------------------------------------------------------------
__global__ __launch_bounds__(256) void vtrans(const unsigned short* __restrict__ qkv,
                                              unsigned short* __restrict__ Vt)
{
    __shared__ unsigned short tile[64][72];
    const int bh = blockIdx.y, b = bh >> 3, h = bh & 7;
    const int s0 = blockIdx.x << 6;
    const int t  = threadIdx.x;
    const int r  = t >> 3;
    const int c8 = (t & 7) << 3;
    const unsigned short* vb = qkv + (long)b * SS * 1536 + 2 * EE + h * DHH;
    #pragma unroll
    for (int rr = 0; rr < 64; rr += 32)
        *(u16x8*)&tile[r + rr][c8] = *(const u16x8*)(vb + (long)(s0 + r + rr) * 1536 + c8);
    __syncthreads();
    #pragma unroll
    for (int rr = 0; rr < 64; rr += 32) {
        const int d = r + rr;
        u16x8 o;
        #pragma unroll
        for (int j = 0; j < 8; ++j) o[j] = tile[c8 + j][d];
        *(u16x8*)(Vt + ((long)bh * DHH + d) * SS + s0 + c8) = o;
    }
}

// ---------------------------------------------------------------------------
// MFMA flash attention v3: 128 q-rows per block, 8 waves (512 thr).
// ---------------------------------------------------------------------------
__global__ __launch_bounds__(512) void flash_mfma(const unsigned short* __restrict__ qkv,
                                                  const unsigned short* __restrict__ Vt,
                                                  unsigned short* __restrict__ o)
{
    __shared__ unsigned short sK[64 * 64];
    __shared__ unsigned short sV[64 * 64];
    __shared__ unsigned short sP[8][16 * 64];
    const int t  = threadIdx.x;
    const int wv = t >> 6, ln = t & 63;
    const int lr = ln & 15, lg = ln >> 4;
    const int bh = blockIdx.y, b = bh >> 3, h = bh & 7;
    const int q0 = (blockIdx.x << 7) + (wv << 4);

    const unsigned short* qb = qkv + (long)b * SS * 1536 + h * DHH;
    const unsigned short* kb = qb + EE;
    const unsigned short* vt = Vt + (long)bh * DHH * SS;
    unsigned short* pw = sP[wv];

    const int srow = ln >> 3;
    const int ucol = ((ln & 7) ^ srow) << 3;

    bf16x8 aq[2];
    #pragma unroll
    for (int c = 0; c < 2; ++c)
        aq[c] = *(const bf16x8*)(qb + (long)(q0 + lr) * 1536 + (c << 5) + (lg << 3));

    float m_[4], l_[4];
    f32x4 accO[4];
    #pragma unroll
    for (int r = 0; r < 4; ++r) { m_[r] = -1e30f; l_[r] = 0.f; }
    #pragma unroll
    for (int n = 0; n < 4; ++n) accO[n] = (f32x4){0.f, 0.f, 0.f, 0.f};

    for (int s0 = 0; s0 < SS; s0 += 64) {
        __syncthreads();
        {
            const int row = (wv << 3) + srow;
            gload16(kb + (long)(s0 + row) * 1536 + ucol, (char*)sK + (wv << 10));
            gload16(vt + (long)row * SS + s0 + ucol,     (char*)sV + (wv << 10));
        }
        __syncthreads();

        f32x4 accS[4];
        #pragma unroll
        for (int sj = 0; sj < 4; ++sj) accS[sj] = (f32x4){0.f, 0.f, 0.f, 0.f};
        #pragma unroll
        for (int c = 0; c < 2; ++c) {
            const int slot = (c << 2) + lg;
            #pragma unroll
            for (int sj = 0; sj < 4; ++sj) {
                const int rw = (sj << 4) + lr;
                const bf16x8 kf = *(const bf16x8*)((const char*)sK + rw * 128 + ((slot ^ (rw & 7)) << 4));
                accS[sj] = __builtin_amdgcn_mfma_f32_16x16x32_bf16(aq[c], kf, accS[sj], 0, 0, 0);
            }
        }
        #pragma unroll
        for (int reg = 0; reg < 4; ++reg) {
            float sc0 = accS[0][reg] * 0.125f, sc1 = accS[1][reg] * 0.125f;
            float sc2 = accS[2][reg] * 0.125f, sc3 = accS[3][reg] * 0.125f;
            float mx = fmaxf(fmaxf(sc0, sc1), fmaxf(sc2, sc3));
            mx = fmaxf(mx, __shfl_xor(mx, 1));
            mx = fmaxf(mx, __shfl_xor(mx, 2));
            mx = fmaxf(mx, __shfl_xor(mx, 4));
            mx = fmaxf(mx, __shfl_xor(mx, 8));
            const float mnew = fmaxf(m_[reg], mx);
            const float f = __expf(m_[reg] - mnew);
            m_[reg] = mnew;
            sc0 = __expf(sc0 - mnew); sc1 = __expf(sc1 - mnew);
            sc2 = __expf(sc2 - mnew); sc3 = __expf(sc3 - mnew);
            accS[0][reg] = sc0; accS[1][reg] = sc1;
            accS[2][reg] = sc2; accS[3][reg] = sc3;
            float ss = sc0 + sc1 + sc2 + sc3;
            ss += __shfl_xor(ss, 1); ss += __shfl_xor(ss, 2);
            ss += __shfl_xor(ss, 4); ss += __shfl_xor(ss, 8);
            l_[reg] = l_[reg] * f + ss;
            #pragma unroll
            for (int n = 0; n < 4; ++n) accO[n][reg] *= f;
        }
        #pragma unroll
        for (int sj = 0; sj < 4; ++sj) {
            #pragma unroll
            for (int reg = 0; reg < 4; ++reg) {
                const int q = (lg << 2) + reg;
                const int s = (sj << 4) + lr;
                const int byte = (q << 7) + (((s >> 3) ^ (q & 7)) << 4) + ((s & 7) << 1);
                *(unsigned short*)((char*)pw + byte) = f2bf(accS[sj][reg]);
            }
        }
        #pragma unroll
        for (int c2 = 0; c2 < 2; ++c2) {
            const int pslot = ((c2 << 2) + lg) ^ (lr & 7);
            const bf16x8 pa = *(const bf16x8*)((const char*)pw + (lr << 7) + (pslot << 4));
            const int vslot = (c2 << 2) + lg;
            #pragma unroll
            for (int n = 0; n < 4; ++n) {
                const int rw = (n << 4) + lr;
                const bf16x8 vf = *(const bf16x8*)((const char*)sV + rw * 128 + ((vslot ^ (rw & 7)) << 4));
                accO[n] = __builtin_amdgcn_mfma_f32_16x16x32_bf16(pa, vf, accO[n], 0, 0, 0);
            }
        }
    }

    #pragma unroll
    for (int reg = 0; reg < 4; ++reg) {
        const float inv = 1.f / l_[reg];
        unsigned short* orow = o + (long)(b * SS + q0 + (lg << 2) + reg) * EE + h * DHH;
        #pragma unroll
        for (int n = 0; n < 4; ++n)
            orow[(n << 4) + lr] = f2bf(accO[n][reg] * inv);
    }
}

// ---------------------------------------------------------------------------
// Fused residual + LayerNorm, in place; also writes bf16 copy.
// ---------------------------------------------------------------------------
__global__ __launch_bounds__(256) void ln_fused(float* __restrict__ x,
                                                unsigned short* __restrict__ xb,
                                                const float* __restrict__ o,
                                                const float* __restrict__ g,
                                                const float* __restrict__ bta)
{
    const long row = blockIdx.x;
    float* xr = x + row * EE;
    unsigned short* hb = xb + row * EE;
    const float* orr = o + row * EE;
    const int t = threadIdx.x;
    const float v0 = xr[t] + orr[t];
    const float v1 = xr[t + 256] + orr[t + 256];
    float s = v0 + v1;
    #pragma unroll
    for (int off = 1; off < 64; off <<= 1) s += __shfl_xor(s, off);
    __shared__ float r1[4], r2[4];
    if ((t & 63) == 0) r1[t >> 6] = s;
    __syncthreads();
    const float mu = (r1[0] + r1[1] + r1[2] + r1[3]) * (1.f / EE);
    const float d0 = v0 - mu, d1 = v1 - mu;
    float q = d0 * d0 + d1 * d1;
    #pragma unroll
    for (int off = 1; off < 64; off <<= 1) q += __shfl_xor(q, off);
    if ((t & 63) == 0) r2[t >> 6] = q;
    __syncthreads();
    const float rs = rsqrtf((r2[0] + r2[1] + r2[2] + r2[3]) * (1.f / EE) + 1e-5f);
    const float y0 = d0 * rs * g[t]       + bta[t];
    const float y1 = d1 * rs * g[t + 256] + bta[t + 256];
    xr[t] = y0;  xr[t + 256] = y1;
    hb[t] = f2bf(y0);  hb[t + 256] = f2bf(y1);
}

// ---------------------------------------------------------------------------
extern "C" void kernel_launch(void* const* d_in, const int* in_sizes, int n_in,
                              void* d_out, int out_size, void* d_ws, size_t ws_size,
                              hipStream_t stream)
{
    const float* inp   = (const float*)d_in[0];
    const float* pe    = (const float*)d_in[1];
    const float* label = (const float*)d_in[2];
    const float* l1w   = (const float*)d_in[3];
    const float* l1b   = (const float*)d_in[4];
    const float* fcw   = (const float*)d_in[5];
    const float* fcb   = (const float*)d_in[6];
    const float* ipw   = (const float*)d_in[7];
    const float* ipb   = (const float*)d_in[8];
    const float* opw   = (const float*)d_in[9];
    const float* opb   = (const float*)d_in[10];
    const float* g1    = (const float*)d_in[11];
    const float* b1    = (const float*)d_in[12];
    const float* g2    = (const float*)d_in[13];
    const float* b2    = (const float*)d_in[14];
    const float* w1    = (const float*)d_in[15];
    const float* bb1   = (const float*)d_in[16];
    const float* w2    = (const float*)d_in[17];
    const float* bb2   = (const float*)d_in[18];

    // ---- workspace layout -------------------------------------------------
    char* wp = (char*)d_ws;
    float* x = (float*)wp;                 wp += (long)BB * SS * EE * 4;
    unsigned short* xb = (unsigned short*)wp;  wp += (long)BB * SS * EE * 2;
    float* bufo = (float*)wp;              wp += (long)BB * SS * EE * 4;
    unsigned short* big = (unsigned short*)wp; wp += (long)BB * SS * DFF_ * 2;
    unsigned short* ob  = (unsigned short*)wp; wp += (long)BB * SS * EE * 2;
    unsigned short* Vtb = (unsigned short*)wp; wp += (long)BB * HH * DHH * SS * 2;
    unsigned short* ipwb = (unsigned short*)wp; wp += (long)LLY * 3 * EE * EE * 2;
    unsigned short* opwb = (unsigned short*)wp; wp += (long)LLY * EE * EE * 2;
    unsigned short* w1b  = (unsigned short*)wp; wp += (long)LLY * DFF_ * EE * 2;
    unsigned short* w2b  = (unsigned short*)wp; wp += (long)LLY * EE * DFF_ * 2;
    unsigned short* l1wb = (unsigned short*)wp; wp += (long)EE * EE * 2;
    unsigned short* labelb = (unsigned short*)wp; wp += (long)CP * EE * 2;
    unsigned short* fcwb   = (unsigned short*)wp; wp += (long)CP * EE * 2;
    float2* stats   = (float2*)wp;         wp += (long)BB * CP * 16 * 8;
    float2* rowstat = (float2*)wp;         wp += (long)BB * CP * 8;
    unsigned short* rawb = (unsigned short*)wp;   // optional [B,CC,S] bf16
    const long raw_bytes = (long)BB * CC * SS * 2;
    const bool bf16raw = ((long)ws_size >= (wp - (char*)d_ws) + raw_bytes);

    float* out0  = (float*)d_out;
    float* attnW = out0 + BB * CC;

    {
        const long n1 = (long)LLY * 3 * EE * EE;
        cvt_bf16<<<(int)((n1 / 4 + 255) / 256), 256, 0, stream>>>(ipw, ipwb, n1, n1);
        const long n2 = (long)LLY * EE * EE;
        cvt_bf16<<<(int)((n2 / 4 + 255) / 256), 256, 0, stream>>>(opw, opwb, n2, n2);
        const long n3 = (long)LLY * DFF_ * EE;
        cvt_bf16<<<(int)((n3 / 4 + 255) / 256), 256, 0, stream>>>(w1, w1b, n3, n3);
        cvt_bf16<<<(int)((n3 / 4 + 255) / 256), 256, 0, stream>>>(w2, w2b, n3, n3);
        const long n4 = (long)EE * EE;
        cvt_bf16<<<(int)((n4 / 4 + 255) / 256), 256, 0, stream>>>(l1w, l1wb, n4, n4);
        const long n5i = (long)CC * EE, n5o = (long)CP * EE;
        cvt_bf16<<<(int)((n5o / 4 + 255) / 256), 256, 0, stream>>>(label, labelb, n5i, n5o);
        cvt_bf16<<<(int)((n5o / 4 + 255) / 256), 256, 0, stream>>>(fcw, fcwb, n5i, n5o);
    }

    const int M = BB * SS;   // 8192

    embed_kernel<<<4096, 256, 0, stream>>>(inp, pe, x, xb);

    for (int l = 0; l < LLY; ++l) {
        gemm_mfma_t<4><<<dim3(64, 12, 1), 256, 0, stream>>>(xb, ipwb + (long)l * 3 * EE * EE,
                                                            ipb + l * 3 * EE, nullptr, big,
                                                            M, 3 * EE, EE, M, 0, 0, 0, 0, 2);
        vtrans<<<dim3(16, 64), 256, 0, stream>>>(big, Vtb);
        flash_mfma<<<dim3(8, 64), 512, 0, stream>>>(big, Vtb, ob);
        gemm_mfma_t<2><<<dim3(64, 8, 1), 256, 0, stream>>>(ob, opwb + (long)l * EE * EE,
                                                           opb + l * EE, bufo, nullptr,
                                                           M, EE, EE, M, 0, 0, 0, 0, 1);
        ln_fused<<<M, 256, 0, stream>>>(x, xb, bufo, g1 + l * EE, b1 + l * EE);
        gemm_mfma_t<4><<<dim3(64, 16, 1), 256, 0, stream>>>(xb, w1b + (long)l * DFF_ * EE,
                                                            bb1 + l * DFF_, nullptr, big,
                                                            M, DFF_, EE, M, 0, 0, 0, 1, 2);
        gemm_mfma_t<2><<<dim3(64, 8, 1), 256, 0, stream>>>(big, w2b + (long)l * EE * DFF_,
                                                           bb2 + l * EE, bufo, nullptr,
                                                           M, EE, DFF_, M, 0, 0, 0, 0, 1);
        ln_fused<<<M, 256, 0, stream>>>(x, xb, bufo, g2 + l * EE, b2 + l * EE);
    }

    // o1 = tanh(x @ l1w^T + l1b) -> bf16 ob
    gemm_mfma_t<2><<<dim3(64, 8, 1), 256, 0, stream>>>(xb, l1wb, l1b, nullptr, ob,
                                                       M, EE, EE, M, 0, 0, 0, 2, 2);
    // raw scores + slice stats
    if (bf16raw)
        gemm_scores_t<true><<<dim3(CP / 128, SS / 128, BB), 256, 0, stream>>>(labelb, ob, attnW, rawb, stats);
    else
        gemm_scores_t<false><<<dim3(CP / 128, SS / 128, BB), 256, 0, stream>>>(labelb, ob, attnW, rawb, stats);
    merge_stats<<<(int)(((long)BB * CP + 255) / 256), 256, 0, stream>>>(stats, rowstat);
    init_out<<<(BB * CC + 255) / 256, 256, 0, stream>>>(out0, fcb);
    // fused final: s-loop, atomic combine (2 waves/row), A-panel L2 reuse
    if (bf16raw)
        gemm_label_final_t<true><<<dim3(71, 1, 8), 256, 0, stream>>>(fcwb, xb, attnW, rawb, rowstat, out0);
    else
        gemm_label_final_t<false><<<dim3(71, 1, 8), 256, 0, stream>>>(fcwb, xb, attnW, rawb, rowstat, out0);
}

// Round 14
// 1092.036 us; speedup vs baseline: 1.1546x; 1.1546x over previous
//
#include <hip/hip_runtime.h>
#include <math.h>

#define BB   8
#define SS   1024
#define EE   512
#define HH   8
#define DHH  64
#define LLY  2
#define CC   8921
#define CP   9088          // C padded to multiple of 128
#define DFF_ 2048

typedef short          bf16x8 __attribute__((ext_vector_type(8)));
typedef float          f32x4  __attribute__((ext_vector_type(4)));
typedef unsigned short u16x4  __attribute__((ext_vector_type(4)));
typedef unsigned short u16x8  __attribute__((ext_vector_type(8)));

__device__ __forceinline__ float bf2f(unsigned short u) {
    return __uint_as_float(((unsigned int)u) << 16);
}
__device__ __forceinline__ unsigned short f2bf(float f) {
    unsigned int u = __float_as_uint(f);
    u = (u + 0x7FFFu + ((u >> 16) & 1u)) >> 16;
    return (unsigned short)u;
}
__device__ __forceinline__ void gload16(const void* g, void* l) {
    __builtin_amdgcn_global_load_lds(
        (const __attribute__((address_space(1))) void*)g,
        (__attribute__((address_space(3))) void*)l, 16, 0, 0);
}

// ---------------------------------------------------------------------------
// f32 -> bf16 convert with zero-pad
// ---------------------------------------------------------------------------
__global__ __launch_bounds__(256) void cvt_bf16(const float* __restrict__ in,
                                                unsigned short* __restrict__ out,
                                                long n_in, long n_out)
{
    const long i4 = ((long)blockIdx.x * 256 + threadIdx.x) * 4;
    if (i4 >= n_out) return;
    u16x4 r;
    if (i4 < n_in) {
        const float4 v = *(const float4*)(in + i4);
        r[0] = f2bf(v.x); r[1] = f2bf(v.y); r[2] = f2bf(v.z); r[3] = f2bf(v.w);
    } else {
        r[0] = r[1] = r[2] = r[3] = 0;
    }
    *(u16x4*)(out + i4) = r;
}

// ---------------------------------------------------------------------------
// embed: x = inputs*sqrt(E) + pe[b]  (pe indexed by batch — source bug kept)
// ---------------------------------------------------------------------------
__global__ __launch_bounds__(256) void embed_kernel(const float* __restrict__ in,
                                                    const float* __restrict__ pe,
                                                    float* __restrict__ x,
                                                    unsigned short* __restrict__ xb)
{
    const long i  = (long)blockIdx.x * 256 + threadIdx.x;
    const int  e4 = (int)(i & 127);
    const int  b  = (int)(i >> 17);
    float4 v = ((const float4*)in)[i];
    const float4 p = ((const float4*)pe)[b * 128 + e4];
    const float sc = 22.627416997969522f;
    v.x = v.x * sc + p.x;  v.y = v.y * sc + p.y;
    v.z = v.z * sc + p.z;  v.w = v.w * sc + p.w;
    ((float4*)x)[i] = v;
    u16x4 h; h[0] = f2bf(v.x); h[1] = f2bf(v.y); h[2] = f2bf(v.z); h[3] = f2bf(v.w);
    ((u16x4*)xb)[i] = h;
}

// ---------------------------------------------------------------------------
// bf16 MFMA GEMM, tile 128 x (32*FN), BK=64. FN=4: 128x128; FN=2: 128x64.
// ---------------------------------------------------------------------------
template<int FN>
__global__ __launch_bounds__(256) void gemm_mfma_t(const unsigned short* __restrict__ A,
                                                   const unsigned short* __restrict__ B,
                                                   const float* __restrict__ bias,
                                                   float* __restrict__ Cf,
                                                   unsigned short* __restrict__ Ch,
                                                   int M, int N, int K, int Mlim,
                                                   long sAz, long sBz, long sCz,
                                                   int act, int mode)
{
    __shared__ unsigned short As[128 * 64];
    __shared__ unsigned short Bs[32 * FN * 64];
    const int t  = threadIdx.x;
    const int wv = t >> 6, ln = t & 63;
    const int wr = wv >> 1, wc = wv & 1;
    const int lr = ln & 15, lg = ln >> 4;
    const int m0 = blockIdx.x * 128, n0 = blockIdx.y * (32 * FN);
    const int z  = blockIdx.z;
    const unsigned short* Ab = A + (long)z * sAz;
    const unsigned short* Bb = B + (long)z * sBz;

    const int srow = ln >> 3;
    const int ucol = ((ln & 7) ^ srow) << 3;

    f32x4 acc[4][FN];
    #pragma unroll
    for (int i = 0; i < 4; ++i)
        #pragma unroll
        for (int j = 0; j < FN; ++j)
            acc[i][j] = (f32x4){0.f, 0.f, 0.f, 0.f};

    int rA[4], rB[FN];
    #pragma unroll
    for (int f = 0; f < 4; ++f) rA[f] = wr * 64 + f * 16 + lr;
    #pragma unroll
    for (int f = 0; f < FN; ++f) rB[f] = wc * (16 * FN) + f * 16 + lr;

    for (int k0 = 0; k0 < K; k0 += 64) {
        __syncthreads();
        #pragma unroll
        for (int c = 0; c < 4; ++c) {
            const int q   = (wv << 2) + c;
            const int row = (q << 3) + srow;
            gload16(Ab + (long)(m0 + row) * K + k0 + ucol, (char*)As + (q << 10));
        }
        #pragma unroll
        for (int c = 0; c < FN; ++c) {
            const int q   = wv * FN + c;
            const int row = (q << 3) + srow;
            gload16(Bb + (long)(n0 + row) * K + k0 + ucol, (char*)Bs + (q << 10));
        }
        __syncthreads();
        #pragma unroll
        for (int kk = 0; kk < 2; ++kk) {
            bf16x8 af[4], bg[FN];
            const int s = (kk << 2) + lg;
            #pragma unroll
            for (int f = 0; f < 4; ++f)
                af[f] = *(const bf16x8*)((const char*)As + rA[f] * 128 + ((s ^ (rA[f] & 7)) << 4));
            #pragma unroll
            for (int f = 0; f < FN; ++f)
                bg[f] = *(const bf16x8*)((const char*)Bs + rB[f] * 128 + ((s ^ (rB[f] & 7)) << 4));
            #pragma unroll
            for (int i = 0; i < 4; ++i)
                #pragma unroll
                for (int j = 0; j < FN; ++j)
                    acc[i][j] = __builtin_amdgcn_mfma_f32_16x16x32_bf16(af[i], bg[j], acc[i][j], 0, 0, 0);
        }
    }

    const long zC = (long)z * sCz;
    #pragma unroll
    for (int fm = 0; fm < 4; ++fm) {
        #pragma unroll
        for (int reg = 0; reg < 4; ++reg) {
            const int gm = m0 + wr * 64 + fm * 16 + lg * 4 + reg;
            if (gm >= Mlim) continue;
            #pragma unroll
            for (int fn = 0; fn < FN; ++fn) {
                const int gn = n0 + wc * (16 * FN) + fn * 16 + lr;
                float v = acc[fm][fn][reg];
                if (bias) v += bias[gn];
                if (act == 1)      v = fmaxf(v, 0.f);
                else if (act == 2) v = tanhf(v);
                if (mode & 1) Cf[zC + (long)gm * N + gn] = v;
                if (mode & 2) Ch[zC + (long)gm * N + gn] = f2bf(v);
            }
        }
    }
}

// ---------------------------------------------------------------------------
// XCD-aware bijective block remap for the scores GEMM (4544 = 8 x 568).
// ---------------------------------------------------------------------------
__device__ __forceinline__ void label_swizzle(int& bx, int& by, int& bz)
{
    const int flat = blockIdx.x + 71 * (blockIdx.y + 8 * blockIdx.z);
    const int swz  = (flat & 7) * 568 + (flat >> 3);
    bx = swz >> 6;            // [0,71)
    by = swz & 7;
    bz = (swz >> 3) & 7;
}

// ---------------------------------------------------------------------------
// Label scores GEMM + per-row-slice softmax stats.
// BF16RAW: raw -> rawb (bf16);  else raw -> attnW (f32, in-place path).
// ---------------------------------------------------------------------------
template<bool BF16RAW>
__global__ __launch_bounds__(256) void gemm_scores_t(const unsigned short* __restrict__ A,   // labelb [CP,E]
                                                     const unsigned short* __restrict__ B,   // o1b [B*S,E]
                                                     float* __restrict__ attnW,              // [B,CC,S]
                                                     unsigned short* __restrict__ rawb,      // [B,CC,S] bf16
                                                     float2* __restrict__ stats)             // [B,CP,16]
{
    __shared__ unsigned short As[128 * 64];
    __shared__ unsigned short Bs[128 * 64];
    int bx, by, bz;
    label_swizzle(bx, by, bz);
    const int t  = threadIdx.x;
    const int wv = t >> 6, ln = t & 63;
    const int wr = wv >> 1, wc = wv & 1;
    const int lr = ln & 15, lg = ln >> 4;
    const int m0 = bx * 128, n0 = by * 128;
    const int z  = bz;
    const unsigned short* Bb = B + (long)z * SS * EE;

    const int srow = ln >> 3;
    const int ucol = ((ln & 7) ^ srow) << 3;

    f32x4 acc[4][4];
    #pragma unroll
    for (int i = 0; i < 4; ++i)
        #pragma unroll
        for (int j = 0; j < 4; ++j)
            acc[i][j] = (f32x4){0.f, 0.f, 0.f, 0.f};

    int rA[4], rB[4];
    #pragma unroll
    for (int f = 0; f < 4; ++f) {
        rA[f] = wr * 64 + f * 16 + lr;
        rB[f] = wc * 64 + f * 16 + lr;
    }

    for (int k0 = 0; k0 < EE; k0 += 64) {
        __syncthreads();
        #pragma unroll
        for (int c = 0; c < 4; ++c) {
            const int q   = (wv << 2) + c;
            const int row = (q << 3) + srow;
            gload16(A  + (long)(m0 + row) * EE + k0 + ucol, (char*)As + (q << 10));
            gload16(Bb + (long)(n0 + row) * EE + k0 + ucol, (char*)Bs + (q << 10));
        }
        __syncthreads();
        #pragma unroll
        for (int kk = 0; kk < 2; ++kk) {
            bf16x8 af[4], bg[4];
            const int s = (kk << 2) + lg;
            #pragma unroll
            for (int f = 0; f < 4; ++f) {
                af[f] = *(const bf16x8*)((const char*)As + rA[f] * 128 + ((s ^ (rA[f] & 7)) << 4));
                bg[f] = *(const bf16x8*)((const char*)Bs + rB[f] * 128 + ((s ^ (rB[f] & 7)) << 4));
            }
            #pragma unroll
            for (int i = 0; i < 4; ++i)
                #pragma unroll
                for (int j = 0; j < 4; ++j)
                    acc[i][j] = __builtin_amdgcn_mfma_f32_16x16x32_bf16(af[i], bg[j], acc[i][j], 0, 0, 0);
        }
    }

    float* aw = attnW + (long)z * CC * SS;
    unsigned short* rb = rawb + (long)z * CC * SS;
    #pragma unroll
    for (int fm = 0; fm < 4; ++fm) {
        #pragma unroll
        for (int reg = 0; reg < 4; ++reg) {
            const int r = m0 + wr * 64 + fm * 16 + lg * 4 + reg;
            const float v0 = acc[fm][0][reg], v1 = acc[fm][1][reg];
            const float v2 = acc[fm][2][reg], v3 = acc[fm][3][reg];
            if (r < CC) {
                #pragma unroll
                for (int fn = 0; fn < 4; ++fn) {
                    const int sn = n0 + wc * 64 + fn * 16 + lr;
                    if (BF16RAW) rb[(long)r * SS + sn] = f2bf(acc[fm][fn][reg]);
                    else         aw[(long)r * SS + sn] = acc[fm][fn][reg];
                }
            }
            float mx = fmaxf(fmaxf(v0, v1), fmaxf(v2, v3));
            mx = fmaxf(mx, __shfl_xor(mx, 1));
            mx = fmaxf(mx, __shfl_xor(mx, 2));
            mx = fmaxf(mx, __shfl_xor(mx, 4));
            mx = fmaxf(mx, __shfl_xor(mx, 8));
            float sm = __expf(v0 - mx) + __expf(v1 - mx) + __expf(v2 - mx) + __expf(v3 - mx);
            sm += __shfl_xor(sm, 1); sm += __shfl_xor(sm, 2);
            sm += __shfl_xor(sm, 4); sm += __shfl_xor(sm, 8);
            if (lr == 0 && r < CC)
                stats[((long)z * CP + r) * 16 + by * 2 + wc] = make_float2(mx, sm);
        }
    }
}

// ---------------------------------------------------------------------------
// merge 16 slice-stats per row -> (max, 1/sum); also init out[b,c] = fc_b[c]
// ---------------------------------------------------------------------------
__global__ __launch_bounds__(256) void merge_stats(const float2* __restrict__ stats,
                                                   float2* __restrict__ rowstat,
                                                   const float* __restrict__ fcb,
                                                   float* __restrict__ out)
{
    const long idx = (long)blockIdx.x * 256 + threadIdx.x;   // z*CP + c
    if (idx >= (long)BB * CP) return;
    const int c = (int)(idx % CP);
    const int z = (int)(idx / CP);
    if (c >= CC) return;
    out[(long)z * CC + c] = fcb[c];
    const float2* s = stats + idx * 16;
    float mx = -1e30f;
    #pragma unroll
    for (int i = 0; i < 16; ++i) mx = fmaxf(mx, s[i].x);
    float tot = 0.f;
    #pragma unroll
    for (int i = 0; i < 16; ++i) tot += s[i].y * __expf(s[i].x - mx);
    rowstat[idx] = make_float2(mx, 1.f / tot);
}

// ---------------------------------------------------------------------------
// Fused final, SY=2 s-loop: one block owns 128 c-rows x 256 s (2 tiles).
// Per s-tile: K-loop D=fcw.x; p=exp(raw-mx)*inv -> f32 p to attnW;
// out partial accumulates lane-locally across both tiles; end: shuffle-reduce
// + one atomicAdd per row per wc-wave (out pre-initialized to fc_b).
// Grid (71,4,8) = 2272 blocks; XCD swizzle x-slowest (2272 = 8 x 284).
// ---------------------------------------------------------------------------
template<bool BF16RAW>
__global__ __launch_bounds__(256) void gemm_label_final_t(const unsigned short* __restrict__ A,  // fcwb [CP,E]
                                                          const unsigned short* __restrict__ B,  // xb [B*S,E]
                                                          float* __restrict__ attnW,             // [B,CC,S] <- p
                                                          const unsigned short* __restrict__ rawb,
                                                          const float2* __restrict__ rowstat,    // [B,CP]
                                                          float* __restrict__ out)               // [B,C]
{
    __shared__ unsigned short As[128 * 64];
    __shared__ unsigned short Bs[128 * 64];
    const int flat = blockIdx.x + 71 * (blockIdx.y + 4 * blockIdx.z);
    const int swz  = (flat & 7) * 284 + (flat >> 3);
    const int bx   = swz >> 5;          // 0..70
    const int rem  = swz & 31;
    const int z    = rem >> 2;          // 0..7
    const int byy  = rem & 3;           // 0..3
    const int t  = threadIdx.x;
    const int wv = t >> 6, ln = t & 63;
    const int wr = wv >> 1, wc = wv & 1;
    const int lr = ln & 15, lg = ln >> 4;
    const int m0 = bx * 128;
    const unsigned short* Bb = B + (long)z * SS * EE;

    const int srow = ln >> 3;
    const int ucol = ((ln & 7) ^ srow) << 3;

    int rA[4], rB[4];
    #pragma unroll
    for (int f = 0; f < 4; ++f) {
        rA[f] = wr * 64 + f * 16 + lr;
        rB[f] = wc * 64 + f * 16 + lr;
    }

    float* aw = attnW + (long)z * CC * SS;
    const unsigned short* rb = rawb + (long)z * CC * SS;
    const float2* rs = rowstat + (long)z * CP;

    float outAcc[4][4];
    #pragma unroll
    for (int i = 0; i < 4; ++i)
        #pragma unroll
        for (int j = 0; j < 4; ++j)
            outAcc[i][j] = 0.f;

    #pragma unroll
    for (int sy = 0; sy < 2; ++sy) {
        const int n0 = ((byy << 1) + sy) << 7;
        f32x4 acc[4][4];
        #pragma unroll
        for (int i = 0; i < 4; ++i)
            #pragma unroll
            for (int j = 0; j < 4; ++j)
                acc[i][j] = (f32x4){0.f, 0.f, 0.f, 0.f};

        for (int k0 = 0; k0 < EE; k0 += 64) {
            __syncthreads();
            #pragma unroll
            for (int c = 0; c < 4; ++c) {
                const int q   = (wv << 2) + c;
                const int row = (q << 3) + srow;
                gload16(A  + (long)(m0 + row) * EE + k0 + ucol, (char*)As + (q << 10));
                gload16(Bb + (long)(n0 + row) * EE + k0 + ucol, (char*)Bs + (q << 10));
            }
            __syncthreads();
            #pragma unroll
            for (int kk = 0; kk < 2; ++kk) {
                bf16x8 af[4], bg[4];
                const int s = (kk << 2) + lg;
                #pragma unroll
                for (int f = 0; f < 4; ++f) {
                    af[f] = *(const bf16x8*)((const char*)As + rA[f] * 128 + ((s ^ (rA[f] & 7)) << 4));
                    bg[f] = *(const bf16x8*)((const char*)Bs + rB[f] * 128 + ((s ^ (rB[f] & 7)) << 4));
                }
                #pragma unroll
                for (int i = 0; i < 4; ++i)
                    #pragma unroll
                    for (int j = 0; j < 4; ++j)
                        acc[i][j] = __builtin_amdgcn_mfma_f32_16x16x32_bf16(af[i], bg[j], acc[i][j], 0, 0, 0);
            }
        }

        #pragma unroll
        for (int fm = 0; fm < 4; ++fm) {
            #pragma unroll
            for (int reg = 0; reg < 4; ++reg) {
                const int r = m0 + wr * 64 + fm * 16 + lg * 4 + reg;
                if (r < CC) {
                    const float2 st = rs[r];
                    #pragma unroll
                    for (int fn = 0; fn < 4; ++fn) {
                        const int sn = n0 + wc * 64 + fn * 16 + lr;
                        const float raw = BF16RAW ? bf2f(rb[(long)r * SS + sn])
                                                  : aw[(long)r * SS + sn];
                        const float p = __expf(raw - st.x) * st.y;
                        aw[(long)r * SS + sn] = p;
                        outAcc[fm][reg] += p * acc[fm][fn][reg];
                    }
                }
            }
        }
    }

    float* outb = out + (long)z * CC;
    #pragma unroll
    for (int fm = 0; fm < 4; ++fm) {
        #pragma unroll
        for (int reg = 0; reg < 4; ++reg) {
            const int r = m0 + wr * 64 + fm * 16 + lg * 4 + reg;
            float pacc = outAcc[fm][reg];
            pacc += __shfl_xor(pacc, 1);
            pacc += __shfl_xor(pacc, 2);
            pacc += __shfl_xor(pacc, 4);
            pacc += __shfl_xor(pacc, 8);
            if (lr == 0 && r < CC) atomicAdd(&outb[r], pacc);   // 2 waves (wc) per row per block
        }
    }
}

// ---------------------------------------------------------------------------
// V transpose: qkv v-part [b,s,(h,d)] -> Vt [bh, d, s]   (bf16)
// ---------------------------------------------------------------------------
__global__ __launch_bounds__(256) void vtrans(const unsigned short* __restrict__ qkv,
                                              unsigned short* __restrict__ Vt)
{
    __shared__ unsigned short tile[64][72];
    const int bh = blockIdx.y, b = bh >> 3, h = bh & 7;
    const int s0 = blockIdx.x << 6;
    const int t  = threadIdx.x;
    const int r  = t >> 3;
    const int c8 = (t & 7) << 3;
    const unsigned short* vb = qkv + (long)b * SS * 1536 + 2 * EE + h * DHH;
    #pragma unroll
    for (int rr = 0; rr < 64; rr += 32)
        *(u16x8*)&tile[r + rr][c8] = *(const u16x8*)(vb + (long)(s0 + r + rr) * 1536 + c8);
    __syncthreads();
    #pragma unroll
    for (int rr = 0; rr < 64; rr += 32) {
        const int d = r + rr;
        u16x8 o;
        #pragma unroll
        for (int j = 0; j < 8; ++j) o[j] = tile[c8 + j][d];
        *(u16x8*)(Vt + ((long)bh * DHH + d) * SS + s0 + c8) = o;
    }
}

// ---------------------------------------------------------------------------
// MFMA flash attention v3: 128 q-rows per block, 8 waves (512 thr).
// ---------------------------------------------------------------------------
__global__ __launch_bounds__(512) void flash_mfma(const unsigned short* __restrict__ qkv,
                                                  const unsigned short* __restrict__ Vt,
                                                  unsigned short* __restrict__ o)
{
    __shared__ unsigned short sK[64 * 64];
    __shared__ unsigned short sV[64 * 64];
    __shared__ unsigned short sP[8][16 * 64];
    const int t  = threadIdx.x;
    const int wv = t >> 6, ln = t & 63;
    const int lr = ln & 15, lg = ln >> 4;
    const int bh = blockIdx.y, b = bh >> 3, h = bh & 7;
    const int q0 = (blockIdx.x << 7) + (wv << 4);

    const unsigned short* qb = qkv + (long)b * SS * 1536 + h * DHH;
    const unsigned short* kb = qb + EE;
    const unsigned short* vt = Vt + (long)bh * DHH * SS;
    unsigned short* pw = sP[wv];

    const int srow = ln >> 3;
    const int ucol = ((ln & 7) ^ srow) << 3;

    bf16x8 aq[2];
    #pragma unroll
    for (int c = 0; c < 2; ++c)
        aq[c] = *(const bf16x8*)(qb + (long)(q0 + lr) * 1536 + (c << 5) + (lg << 3));

    float m_[4], l_[4];
    f32x4 accO[4];
    #pragma unroll
    for (int r = 0; r < 4; ++r) { m_[r] = -1e30f; l_[r] = 0.f; }
    #pragma unroll
    for (int n = 0; n < 4; ++n) accO[n] = (f32x4){0.f, 0.f, 0.f, 0.f};

    for (int s0 = 0; s0 < SS; s0 += 64) {
        __syncthreads();
        {
            const int row = (wv << 3) + srow;
            gload16(kb + (long)(s0 + row) * 1536 + ucol, (char*)sK + (wv << 10));
            gload16(vt + (long)row * SS + s0 + ucol,     (char*)sV + (wv << 10));
        }
        __syncthreads();

        f32x4 accS[4];
        #pragma unroll
        for (int sj = 0; sj < 4; ++sj) accS[sj] = (f32x4){0.f, 0.f, 0.f, 0.f};
        #pragma unroll
        for (int c = 0; c < 2; ++c) {
            const int slot = (c << 2) + lg;
            #pragma unroll
            for (int sj = 0; sj < 4; ++sj) {
                const int rw = (sj << 4) + lr;
                const bf16x8 kf = *(const bf16x8*)((const char*)sK + rw * 128 + ((slot ^ (rw & 7)) << 4));
                accS[sj] = __builtin_amdgcn_mfma_f32_16x16x32_bf16(aq[c], kf, accS[sj], 0, 0, 0);
            }
        }
        #pragma unroll
        for (int reg = 0; reg < 4; ++reg) {
            float sc0 = accS[0][reg] * 0.125f, sc1 = accS[1][reg] * 0.125f;
            float sc2 = accS[2][reg] * 0.125f, sc3 = accS[3][reg] * 0.125f;
            float mx = fmaxf(fmaxf(sc0, sc1), fmaxf(sc2, sc3));
            mx = fmaxf(mx, __shfl_xor(mx, 1));
            mx = fmaxf(mx, __shfl_xor(mx, 2));
            mx = fmaxf(mx, __shfl_xor(mx, 4));
            mx = fmaxf(mx, __shfl_xor(mx, 8));
            const float mnew = fmaxf(m_[reg], mx);
            const float f = __expf(m_[reg] - mnew);
            m_[reg] = mnew;
            sc0 = __expf(sc0 - mnew); sc1 = __expf(sc1 - mnew);
            sc2 = __expf(sc2 - mnew); sc3 = __expf(sc3 - mnew);
            accS[0][reg] = sc0; accS[1][reg] = sc1;
            accS[2][reg] = sc2; accS[3][reg] = sc3;
            float ss = sc0 + sc1 + sc2 + sc3;
            ss += __shfl_xor(ss, 1); ss += __shfl_xor(ss, 2);
            ss += __shfl_xor(ss, 4); ss += __shfl_xor(ss, 8);
            l_[reg] = l_[reg] * f + ss;
            #pragma unroll
            for (int n = 0; n < 4; ++n) accO[n][reg] *= f;
        }
        #pragma unroll
        for (int sj = 0; sj < 4; ++sj) {
            #pragma unroll
            for (int reg = 0; reg < 4; ++reg) {
                const int q = (lg << 2) + reg;
                const int s = (sj << 4) + lr;
                const int byte = (q << 7) + (((s >> 3) ^ (q & 7)) << 4) + ((s & 7) << 1);
                *(unsigned short*)((char*)pw + byte) = f2bf(accS[sj][reg]);
            }
        }
        #pragma unroll
        for (int c2 = 0; c2 < 2; ++c2) {
            const int pslot = ((c2 << 2) + lg) ^ (lr & 7);
            const bf16x8 pa = *(const bf16x8*)((const char*)pw + (lr << 7) + (pslot << 4));
            const int vslot = (c2 << 2) + lg;
            #pragma unroll
            for (int n = 0; n < 4; ++n) {
                const int rw = (n << 4) + lr;
                const bf16x8 vf = *(const bf16x8*)((const char*)sV + rw * 128 + ((vslot ^ (rw & 7)) << 4));
                accO[n] = __builtin_amdgcn_mfma_f32_16x16x32_bf16(pa, vf, accO[n], 0, 0, 0);
            }
        }
    }

    #pragma unroll
    for (int reg = 0; reg < 4; ++reg) {
        const float inv = 1.f / l_[reg];
        unsigned short* orow = o + (long)(b * SS + q0 + (lg << 2) + reg) * EE + h * DHH;
        #pragma unroll
        for (int n = 0; n < 4; ++n)
            orow[(n << 4) + lr] = f2bf(accO[n][reg] * inv);
    }
}

// ---------------------------------------------------------------------------
// Fused residual + LayerNorm, in place; also writes bf16 copy.
// ---------------------------------------------------------------------------
__global__ __launch_bounds__(256) void ln_fused(float* __restrict__ x,
                                                unsigned short* __restrict__ xb,
                                                const float* __restrict__ o,
                                                const float* __restrict__ g,
                                                const float* __restrict__ bta)
{
    const long row = blockIdx.x;
    float* xr = x + row * EE;
    unsigned short* hb = xb + row * EE;
    const float* orr = o + row * EE;
    const int t = threadIdx.x;
    const float v0 = xr[t] + orr[t];
    const float v1 = xr[t + 256] + orr[t + 256];
    float s = v0 + v1;
    #pragma unroll
    for (int off = 1; off < 64; off <<= 1) s += __shfl_xor(s, off);
    __shared__ float r1[4], r2[4];
    if ((t & 63) == 0) r1[t >> 6] = s;
    __syncthreads();
    const float mu = (r1[0] + r1[1] + r1[2] + r1[3]) * (1.f / EE);
    const float d0 = v0 - mu, d1 = v1 - mu;
    float q = d0 * d0 + d1 * d1;
    #pragma unroll
    for (int off = 1; off < 64; off <<= 1) q += __shfl_xor(q, off);
    if ((t & 63) == 0) r2[t >> 6] = q;
    __syncthreads();
    const float rs = rsqrtf((r2[0] + r2[1] + r2[2] + r2[3]) * (1.f / EE) + 1e-5f);
    const float y0 = d0 * rs * g[t]       + bta[t];
    const float y1 = d1 * rs * g[t + 256] + bta[t + 256];
    xr[t] = y0;  xr[t + 256] = y1;
    hb[t] = f2bf(y0);  hb[t + 256] = f2bf(y1);
}

// ---------------------------------------------------------------------------
extern "C" void kernel_launch(void* const* d_in, const int* in_sizes, int n_in,
                              void* d_out, int out_size, void* d_ws, size_t ws_size,
                              hipStream_t stream)
{
    const float* inp   = (const float*)d_in[0];
    const float* pe    = (const float*)d_in[1];
    const float* label = (const float*)d_in[2];
    const float* l1w   = (const float*)d_in[3];
    const float* l1b   = (const float*)d_in[4];
    const float* fcw   = (const float*)d_in[5];
    const float* fcb   = (const float*)d_in[6];
    const float* ipw   = (const float*)d_in[7];
    const float* ipb   = (const float*)d_in[8];
    const float* opw   = (const float*)d_in[9];
    const float* opb   = (const float*)d_in[10];
    const float* g1    = (const float*)d_in[11];
    const float* b1    = (const float*)d_in[12];
    const float* g2    = (const float*)d_in[13];
    const float* b2    = (const float*)d_in[14];
    const float* w1    = (const float*)d_in[15];
    const float* bb1   = (const float*)d_in[16];
    const float* w2    = (const float*)d_in[17];
    const float* bb2   = (const float*)d_in[18];

    // ---- workspace layout -------------------------------------------------
    char* wp = (char*)d_ws;
    float* x = (float*)wp;                 wp += (long)BB * SS * EE * 4;
    unsigned short* xb = (unsigned short*)wp;  wp += (long)BB * SS * EE * 2;
    float* bufo = (float*)wp;              wp += (long)BB * SS * EE * 4;
    unsigned short* big = (unsigned short*)wp; wp += (long)BB * SS * DFF_ * 2;
    unsigned short* ob  = (unsigned short*)wp; wp += (long)BB * SS * EE * 2;
    unsigned short* Vtb = (unsigned short*)wp; wp += (long)BB * HH * DHH * SS * 2;
    unsigned short* ipwb = (unsigned short*)wp; wp += (long)LLY * 3 * EE * EE * 2;
    unsigned short* opwb = (unsigned short*)wp; wp += (long)LLY * EE * EE * 2;
    unsigned short* w1b  = (unsigned short*)wp; wp += (long)LLY * DFF_ * EE * 2;
    unsigned short* w2b  = (unsigned short*)wp; wp += (long)LLY * EE * DFF_ * 2;
    unsigned short* l1wb = (unsigned short*)wp; wp += (long)EE * EE * 2;
    unsigned short* labelb = (unsigned short*)wp; wp += (long)CP * EE * 2;
    unsigned short* fcwb   = (unsigned short*)wp; wp += (long)CP * EE * 2;
    float2* stats   = (float2*)wp;         wp += (long)BB * CP * 16 * 8;
    float2* rowstat = (float2*)wp;         wp += (long)BB * CP * 8;
    unsigned short* rawb = (unsigned short*)wp;   // optional [B,CC,S] bf16
    const long raw_bytes = (long)BB * CC * SS * 2;
    const bool bf16raw = ((long)ws_size >= (wp - (char*)d_ws) + raw_bytes);

    float* out0  = (float*)d_out;
    float* attnW = out0 + BB * CC;

    {
        const long n1 = (long)LLY * 3 * EE * EE;
        cvt_bf16<<<(int)((n1 / 4 + 255) / 256), 256, 0, stream>>>(ipw, ipwb, n1, n1);
        const long n2 = (long)LLY * EE * EE;
        cvt_bf16<<<(int)((n2 / 4 + 255) / 256), 256, 0, stream>>>(opw, opwb, n2, n2);
        const long n3 = (long)LLY * DFF_ * EE;
        cvt_bf16<<<(int)((n3 / 4 + 255) / 256), 256, 0, stream>>>(w1, w1b, n3, n3);
        cvt_bf16<<<(int)((n3 / 4 + 255) / 256), 256, 0, stream>>>(w2, w2b, n3, n3);
        const long n4 = (long)EE * EE;
        cvt_bf16<<<(int)((n4 / 4 + 255) / 256), 256, 0, stream>>>(l1w, l1wb, n4, n4);
        const long n5i = (long)CC * EE, n5o = (long)CP * EE;
        cvt_bf16<<<(int)((n5o / 4 + 255) / 256), 256, 0, stream>>>(label, labelb, n5i, n5o);
        cvt_bf16<<<(int)((n5o / 4 + 255) / 256), 256, 0, stream>>>(fcw, fcwb, n5i, n5o);
    }

    const int M = BB * SS;   // 8192

    embed_kernel<<<4096, 256, 0, stream>>>(inp, pe, x, xb);

    for (int l = 0; l < LLY; ++l) {
        gemm_mfma_t<4><<<dim3(64, 12, 1), 256, 0, stream>>>(xb, ipwb + (long)l * 3 * EE * EE,
                                                            ipb + l * 3 * EE, nullptr, big,
                                                            M, 3 * EE, EE, M, 0, 0, 0, 0, 2);
        vtrans<<<dim3(16, 64), 256, 0, stream>>>(big, Vtb);
        flash_mfma<<<dim3(8, 64), 512, 0, stream>>>(big, Vtb, ob);
        gemm_mfma_t<2><<<dim3(64, 8, 1), 256, 0, stream>>>(ob, opwb + (long)l * EE * EE,
                                                           opb + l * EE, bufo, nullptr,
                                                           M, EE, EE, M, 0, 0, 0, 0, 1);
        ln_fused<<<M, 256, 0, stream>>>(x, xb, bufo, g1 + l * EE, b1 + l * EE);
        gemm_mfma_t<4><<<dim3(64, 16, 1), 256, 0, stream>>>(xb, w1b + (long)l * DFF_ * EE,
                                                            bb1 + l * DFF_, nullptr, big,
                                                            M, DFF_, EE, M, 0, 0, 0, 1, 2);
        gemm_mfma_t<2><<<dim3(64, 8, 1), 256, 0, stream>>>(big, w2b + (long)l * EE * DFF_,
                                                           bb2 + l * EE, bufo, nullptr,
                                                           M, EE, DFF_, M, 0, 0, 0, 0, 1);
        ln_fused<<<M, 256, 0, stream>>>(x, xb, bufo, g2 + l * EE, b2 + l * EE);
    }

    // o1 = tanh(x @ l1w^T + l1b) -> bf16 ob
    gemm_mfma_t<2><<<dim3(64, 8, 1), 256, 0, stream>>>(xb, l1wb, l1b, nullptr, ob,
                                                       M, EE, EE, M, 0, 0, 0, 2, 2);
    // raw scores + slice stats
    if (bf16raw)
        gemm_scores_t<true><<<dim3(CP / 128, SS / 128, BB), 256, 0, stream>>>(labelb, ob, attnW, rawb, stats);
    else
        gemm_scores_t<false><<<dim3(CP / 128, SS / 128, BB), 256, 0, stream>>>(labelb, ob, attnW, rawb, stats);
    // merge stats + init out = fc_b (fused)
    merge_stats<<<(int)(((long)BB * CP + 255) / 256), 256, 0, stream>>>(stats, rowstat, fcb, out0);
    // fused final: SY=2 s-loop, atomic combine, XCD-swizzled
    if (bf16raw)
        gemm_label_final_t<true><<<dim3(71, 4, 8), 256, 0, stream>>>(fcwb, xb, attnW, rawb, rowstat, out0);
    else
        gemm_label_final_t<false><<<dim3(71, 4, 8), 256, 0, stream>>>(fcwb, xb, attnW, rawb, rowstat, out0);
}

// Round 15
// 1010.797 us; speedup vs baseline: 1.2474x; 1.0804x over previous
//
#include <hip/hip_runtime.h>
#include <math.h>

#define BB   8
#define SS   1024
#define EE   512
#define HH   8
#define DHH  64
#define LLY  2
#define CC   8921
#define CP   9088          // C padded to multiple of 128
#define DFF_ 2048

typedef short          bf16x8 __attribute__((ext_vector_type(8)));
typedef float          f32x4  __attribute__((ext_vector_type(4)));
typedef unsigned short u16x4  __attribute__((ext_vector_type(4)));
typedef unsigned short u16x8  __attribute__((ext_vector_type(8)));

__device__ __forceinline__ float bf2f(unsigned short u) {
    return __uint_as_float(((unsigned int)u) << 16);
}
__device__ __forceinline__ unsigned short f2bf(float f) {
    unsigned int u = __float_as_uint(f);
    u = (u + 0x7FFFu + ((u >> 16) & 1u)) >> 16;
    return (unsigned short)u;
}
__device__ __forceinline__ void gload16(const void* g, void* l) {
    __builtin_amdgcn_global_load_lds(
        (const __attribute__((address_space(1))) void*)g,
        (__attribute__((address_space(3))) void*)l, 16, 0, 0);
}

// ---------------------------------------------------------------------------
// f32 -> bf16 convert with zero-pad
// ---------------------------------------------------------------------------
__global__ __launch_bounds__(256) void cvt_bf16(const float* __restrict__ in,
                                                unsigned short* __restrict__ out,
                                                long n_in, long n_out)
{
    const long i4 = ((long)blockIdx.x * 256 + threadIdx.x) * 4;
    if (i4 >= n_out) return;
    u16x4 r;
    if (i4 < n_in) {
        const float4 v = *(const float4*)(in + i4);
        r[0] = f2bf(v.x); r[1] = f2bf(v.y); r[2] = f2bf(v.z); r[3] = f2bf(v.w);
    } else {
        r[0] = r[1] = r[2] = r[3] = 0;
    }
    *(u16x4*)(out + i4) = r;
}

// ---------------------------------------------------------------------------
// embed: x = inputs*sqrt(E) + pe[b]  (pe indexed by batch — source bug kept)
// ---------------------------------------------------------------------------
__global__ __launch_bounds__(256) void embed_kernel(const float* __restrict__ in,
                                                    const float* __restrict__ pe,
                                                    float* __restrict__ x,
                                                    unsigned short* __restrict__ xb)
{
    const long i  = (long)blockIdx.x * 256 + threadIdx.x;
    const int  e4 = (int)(i & 127);
    const int  b  = (int)(i >> 17);
    float4 v = ((const float4*)in)[i];
    const float4 p = ((const float4*)pe)[b * 128 + e4];
    const float sc = 22.627416997969522f;
    v.x = v.x * sc + p.x;  v.y = v.y * sc + p.y;
    v.z = v.z * sc + p.z;  v.w = v.w * sc + p.w;
    ((float4*)x)[i] = v;
    u16x4 h; h[0] = f2bf(v.x); h[1] = f2bf(v.y); h[2] = f2bf(v.z); h[3] = f2bf(v.w);
    ((u16x4*)xb)[i] = h;
}

// ---------------------------------------------------------------------------
// bf16 MFMA GEMM, tile 128 x (32*FN), BK=64. FN=4: 128x128; FN=2: 128x64.
// ---------------------------------------------------------------------------
template<int FN>
__global__ __launch_bounds__(256) void gemm_mfma_t(const unsigned short* __restrict__ A,
                                                   const unsigned short* __restrict__ B,
                                                   const float* __restrict__ bias,
                                                   float* __restrict__ Cf,
                                                   unsigned short* __restrict__ Ch,
                                                   int M, int N, int K, int Mlim,
                                                   long sAz, long sBz, long sCz,
                                                   int act, int mode)
{
    __shared__ unsigned short As[128 * 64];
    __shared__ unsigned short Bs[32 * FN * 64];
    const int t  = threadIdx.x;
    const int wv = t >> 6, ln = t & 63;
    const int wr = wv >> 1, wc = wv & 1;
    const int lr = ln & 15, lg = ln >> 4;
    const int m0 = blockIdx.x * 128, n0 = blockIdx.y * (32 * FN);
    const int z  = blockIdx.z;
    const unsigned short* Ab = A + (long)z * sAz;
    const unsigned short* Bb = B + (long)z * sBz;

    const int srow = ln >> 3;
    const int ucol = ((ln & 7) ^ srow) << 3;

    f32x4 acc[4][FN];
    #pragma unroll
    for (int i = 0; i < 4; ++i)
        #pragma unroll
        for (int j = 0; j < FN; ++j)
            acc[i][j] = (f32x4){0.f, 0.f, 0.f, 0.f};

    int rA[4], rB[FN];
    #pragma unroll
    for (int f = 0; f < 4; ++f) rA[f] = wr * 64 + f * 16 + lr;
    #pragma unroll
    for (int f = 0; f < FN; ++f) rB[f] = wc * (16 * FN) + f * 16 + lr;

    for (int k0 = 0; k0 < K; k0 += 64) {
        __syncthreads();
        #pragma unroll
        for (int c = 0; c < 4; ++c) {
            const int q   = (wv << 2) + c;
            const int row = (q << 3) + srow;
            gload16(Ab + (long)(m0 + row) * K + k0 + ucol, (char*)As + (q << 10));
        }
        #pragma unroll
        for (int c = 0; c < FN; ++c) {
            const int q   = wv * FN + c;
            const int row = (q << 3) + srow;
            gload16(Bb + (long)(n0 + row) * K + k0 + ucol, (char*)Bs + (q << 10));
        }
        __syncthreads();
        #pragma unroll
        for (int kk = 0; kk < 2; ++kk) {
            bf16x8 af[4], bg[FN];
            const int s = (kk << 2) + lg;
            #pragma unroll
            for (int f = 0; f < 4; ++f)
                af[f] = *(const bf16x8*)((const char*)As + rA[f] * 128 + ((s ^ (rA[f] & 7)) << 4));
            #pragma unroll
            for (int f = 0; f < FN; ++f)
                bg[f] = *(const bf16x8*)((const char*)Bs + rB[f] * 128 + ((s ^ (rB[f] & 7)) << 4));
            #pragma unroll
            for (int i = 0; i < 4; ++i)
                #pragma unroll
                for (int j = 0; j < FN; ++j)
                    acc[i][j] = __builtin_amdgcn_mfma_f32_16x16x32_bf16(af[i], bg[j], acc[i][j], 0, 0, 0);
        }
    }

    const long zC = (long)z * sCz;
    #pragma unroll
    for (int fm = 0; fm < 4; ++fm) {
        #pragma unroll
        for (int reg = 0; reg < 4; ++reg) {
            const int gm = m0 + wr * 64 + fm * 16 + lg * 4 + reg;
            if (gm >= Mlim) continue;
            #pragma unroll
            for (int fn = 0; fn < FN; ++fn) {
                const int gn = n0 + wc * (16 * FN) + fn * 16 + lr;
                float v = acc[fm][fn][reg];
                if (bias) v += bias[gn];
                if (act == 1)      v = fmaxf(v, 0.f);
                else if (act == 2) v = tanhf(v);
                if (mode & 1) Cf[zC + (long)gm * N + gn] = v;
                if (mode & 2) Ch[zC + (long)gm * N + gn] = f2bf(v);
            }
        }
    }
}

// ---------------------------------------------------------------------------
// XCD-aware bijective block remap for the label GEMMs (4544 = 8 x 568).
// ---------------------------------------------------------------------------
__device__ __forceinline__ void label_swizzle(int& bx, int& by, int& bz)
{
    const int flat = blockIdx.x + 71 * (blockIdx.y + 8 * blockIdx.z);
    const int swz  = (flat & 7) * 568 + (flat >> 3);
    bx = swz >> 6;            // [0,71)
    by = swz & 7;
    bz = (swz >> 3) & 7;
}

// ---------------------------------------------------------------------------
// Label scores GEMM + per-row-slice softmax stats.
// BF16RAW: raw -> rawb (bf16);  else raw -> attnW (f32, in-place path).
// ---------------------------------------------------------------------------
template<bool BF16RAW>
__global__ __launch_bounds__(256) void gemm_scores_t(const unsigned short* __restrict__ A,   // labelb [CP,E]
                                                     const unsigned short* __restrict__ B,   // o1b [B*S,E]
                                                     float* __restrict__ attnW,              // [B,CC,S]
                                                     unsigned short* __restrict__ rawb,      // [B,CC,S] bf16
                                                     float2* __restrict__ stats)             // [B,CP,16]
{
    __shared__ unsigned short As[128 * 64];
    __shared__ unsigned short Bs[128 * 64];
    int bx, by, bz;
    label_swizzle(bx, by, bz);
    const int t  = threadIdx.x;
    const int wv = t >> 6, ln = t & 63;
    const int wr = wv >> 1, wc = wv & 1;
    const int lr = ln & 15, lg = ln >> 4;
    const int m0 = bx * 128, n0 = by * 128;
    const int z  = bz;
    const unsigned short* Bb = B + (long)z * SS * EE;

    const int srow = ln >> 3;
    const int ucol = ((ln & 7) ^ srow) << 3;

    f32x4 acc[4][4];
    #pragma unroll
    for (int i = 0; i < 4; ++i)
        #pragma unroll
        for (int j = 0; j < 4; ++j)
            acc[i][j] = (f32x4){0.f, 0.f, 0.f, 0.f};

    int rA[4], rB[4];
    #pragma unroll
    for (int f = 0; f < 4; ++f) {
        rA[f] = wr * 64 + f * 16 + lr;
        rB[f] = wc * 64 + f * 16 + lr;
    }

    for (int k0 = 0; k0 < EE; k0 += 64) {
        __syncthreads();
        #pragma unroll
        for (int c = 0; c < 4; ++c) {
            const int q   = (wv << 2) + c;
            const int row = (q << 3) + srow;
            gload16(A  + (long)(m0 + row) * EE + k0 + ucol, (char*)As + (q << 10));
            gload16(Bb + (long)(n0 + row) * EE + k0 + ucol, (char*)Bs + (q << 10));
        }
        __syncthreads();
        #pragma unroll
        for (int kk = 0; kk < 2; ++kk) {
            bf16x8 af[4], bg[4];
            const int s = (kk << 2) + lg;
            #pragma unroll
            for (int f = 0; f < 4; ++f) {
                af[f] = *(const bf16x8*)((const char*)As + rA[f] * 128 + ((s ^ (rA[f] & 7)) << 4));
                bg[f] = *(const bf16x8*)((const char*)Bs + rB[f] * 128 + ((s ^ (rB[f] & 7)) << 4));
            }
            #pragma unroll
            for (int i = 0; i < 4; ++i)
                #pragma unroll
                for (int j = 0; j < 4; ++j)
                    acc[i][j] = __builtin_amdgcn_mfma_f32_16x16x32_bf16(af[i], bg[j], acc[i][j], 0, 0, 0);
        }
    }

    float* aw = attnW + (long)z * CC * SS;
    unsigned short* rb = rawb + (long)z * CC * SS;
    #pragma unroll
    for (int fm = 0; fm < 4; ++fm) {
        #pragma unroll
        for (int reg = 0; reg < 4; ++reg) {
            const int r = m0 + wr * 64 + fm * 16 + lg * 4 + reg;
            const float v0 = acc[fm][0][reg], v1 = acc[fm][1][reg];
            const float v2 = acc[fm][2][reg], v3 = acc[fm][3][reg];
            if (r < CC) {
                #pragma unroll
                for (int fn = 0; fn < 4; ++fn) {
                    const int sn = n0 + wc * 64 + fn * 16 + lr;
                    if (BF16RAW) rb[(long)r * SS + sn] = f2bf(acc[fm][fn][reg]);
                    else         aw[(long)r * SS + sn] = acc[fm][fn][reg];
                }
            }
            float mx = fmaxf(fmaxf(v0, v1), fmaxf(v2, v3));
            mx = fmaxf(mx, __shfl_xor(mx, 1));
            mx = fmaxf(mx, __shfl_xor(mx, 2));
            mx = fmaxf(mx, __shfl_xor(mx, 4));
            mx = fmaxf(mx, __shfl_xor(mx, 8));
            float sm = __expf(v0 - mx) + __expf(v1 - mx) + __expf(v2 - mx) + __expf(v3 - mx);
            sm += __shfl_xor(sm, 1); sm += __shfl_xor(sm, 2);
            sm += __shfl_xor(sm, 4); sm += __shfl_xor(sm, 8);
            if (lr == 0 && r < CC)
                stats[((long)z * CP + r) * 16 + by * 2 + wc] = make_float2(mx, sm);
        }
    }
}

// ---------------------------------------------------------------------------
// merge 16 slice-stats per row -> (max, 1/sum); also init out[b,c] = fc_b[c]
// ---------------------------------------------------------------------------
__global__ __launch_bounds__(256) void merge_stats(const float2* __restrict__ stats,
                                                   float2* __restrict__ rowstat,
                                                   const float* __restrict__ fcb,
                                                   float* __restrict__ out)
{
    const long idx = (long)blockIdx.x * 256 + threadIdx.x;   // z*CP + c
    if (idx >= (long)BB * CP) return;
    const int c = (int)(idx % CP);
    const int z = (int)(idx / CP);
    if (c >= CC) return;
    out[(long)z * CC + c] = fcb[c];
    const float2* s = stats + idx * 16;
    float mx = -1e30f;
    #pragma unroll
    for (int i = 0; i < 16; ++i) mx = fmaxf(mx, s[i].x);
    float tot = 0.f;
    #pragma unroll
    for (int i = 0; i < 16; ++i) tot += s[i].y * __expf(s[i].x - mx);
    rowstat[idx] = make_float2(mx, 1.f / tot);
}

// ---------------------------------------------------------------------------
// Fused final (round-11 per-tile version — best measured): D = fcw.x (MFMA);
// p = exp(raw-mx)*inv -> f32 p to attnW; out += sum p*D via shuffle+atomic.
// Grid (71,8,8) with XCD swizzle.
// ---------------------------------------------------------------------------
template<bool BF16RAW>
__global__ __launch_bounds__(256) void gemm_label_final_t(const unsigned short* __restrict__ A,  // fcwb [CP,E]
                                                          const unsigned short* __restrict__ B,  // xb [B*S,E]
                                                          float* __restrict__ attnW,             // [B,CC,S] <- p
                                                          const unsigned short* __restrict__ rawb,
                                                          const float2* __restrict__ rowstat,    // [B,CP]
                                                          float* __restrict__ out)               // [B,C]
{
    __shared__ unsigned short As[128 * 64];
    __shared__ unsigned short Bs[128 * 64];
    int bx, by, bz;
    label_swizzle(bx, by, bz);
    const int t  = threadIdx.x;
    const int wv = t >> 6, ln = t & 63;
    const int wr = wv >> 1, wc = wv & 1;
    const int lr = ln & 15, lg = ln >> 4;
    const int m0 = bx * 128, n0 = by * 128;
    const int z  = bz;
    const unsigned short* Bb = B + (long)z * SS * EE;

    const int srow = ln >> 3;
    const int ucol = ((ln & 7) ^ srow) << 3;

    f32x4 acc[4][4];
    #pragma unroll
    for (int i = 0; i < 4; ++i)
        #pragma unroll
        for (int j = 0; j < 4; ++j)
            acc[i][j] = (f32x4){0.f, 0.f, 0.f, 0.f};

    int rA[4], rB[4];
    #pragma unroll
    for (int f = 0; f < 4; ++f) {
        rA[f] = wr * 64 + f * 16 + lr;
        rB[f] = wc * 64 + f * 16 + lr;
    }

    for (int k0 = 0; k0 < EE; k0 += 64) {
        __syncthreads();
        #pragma unroll
        for (int c = 0; c < 4; ++c) {
            const int q   = (wv << 2) + c;
            const int row = (q << 3) + srow;
            gload16(A  + (long)(m0 + row) * EE + k0 + ucol, (char*)As + (q << 10));
            gload16(Bb + (long)(n0 + row) * EE + k0 + ucol, (char*)Bs + (q << 10));
        }
        __syncthreads();
        #pragma unroll
        for (int kk = 0; kk < 2; ++kk) {
            bf16x8 af[4], bg[4];
            const int s = (kk << 2) + lg;
            #pragma unroll
            for (int f = 0; f < 4; ++f) {
                af[f] = *(const bf16x8*)((const char*)As + rA[f] * 128 + ((s ^ (rA[f] & 7)) << 4));
                bg[f] = *(const bf16x8*)((const char*)Bs + rB[f] * 128 + ((s ^ (rB[f] & 7)) << 4));
            }
            #pragma unroll
            for (int i = 0; i < 4; ++i)
                #pragma unroll
                for (int j = 0; j < 4; ++j)
                    acc[i][j] = __builtin_amdgcn_mfma_f32_16x16x32_bf16(af[i], bg[j], acc[i][j], 0, 0, 0);
        }
    }

    float* aw = attnW + (long)z * CC * SS;
    const unsigned short* rb = rawb + (long)z * CC * SS;
    const float2* rs = rowstat + (long)z * CP;
    float* outb = out + (long)z * CC;
    #pragma unroll
    for (int fm = 0; fm < 4; ++fm) {
        #pragma unroll
        for (int reg = 0; reg < 4; ++reg) {
            const int r = m0 + wr * 64 + fm * 16 + lg * 4 + reg;
            float pacc = 0.f;
            if (r < CC) {
                const float2 st = rs[r];
                #pragma unroll
                for (int fn = 0; fn < 4; ++fn) {
                    const int sn = n0 + wc * 64 + fn * 16 + lr;
                    const float raw = BF16RAW ? bf2f(rb[(long)r * SS + sn])
                                              : aw[(long)r * SS + sn];
                    const float p = __expf(raw - st.x) * st.y;
                    aw[(long)r * SS + sn] = p;
                    pacc += p * acc[fm][fn][reg];
                }
            }
            pacc += __shfl_xor(pacc, 1);
            pacc += __shfl_xor(pacc, 2);
            pacc += __shfl_xor(pacc, 4);
            pacc += __shfl_xor(pacc, 8);
            if (lr == 0 && r < CC) atomicAdd(&outb[r], pacc);
        }
    }
}

// ---------------------------------------------------------------------------
// V transpose: qkv v-part [b,s,(h,d)] -> Vt [bh, d, s]   (bf16)
// ---------------------------------------------------------------------------
__global__ __launch_bounds__(256) void vtrans(const unsigned short* __restrict__ qkv,
                                              unsigned short* __restrict__ Vt)
{
    __shared__ unsigned short tile[64][72];
    const int bh = blockIdx.y, b = bh >> 3, h = bh & 7;
    const int s0 = blockIdx.x << 6;
    const int t  = threadIdx.x;
    const int r  = t >> 3;
    const int c8 = (t & 7) << 3;
    const unsigned short* vb = qkv + (long)b * SS * 1536 + 2 * EE + h * DHH;
    #pragma unroll
    for (int rr = 0; rr < 64; rr += 32)
        *(u16x8*)&tile[r + rr][c8] = *(const u16x8*)(vb + (long)(s0 + r + rr) * 1536 + c8);
    __syncthreads();
    #pragma unroll
    for (int rr = 0; rr < 64; rr += 32) {
        const int d = r + rr;
        u16x8 o;
        #pragma unroll
        for (int j = 0; j < 8; ++j) o[j] = tile[c8 + j][d];
        *(u16x8*)(Vt + ((long)bh * DHH + d) * SS + s0 + c8) = o;
    }
}

// ---------------------------------------------------------------------------
// MFMA flash attention v3: 128 q-rows per block, 8 waves (512 thr).
// ---------------------------------------------------------------------------
__global__ __launch_bounds__(512) void flash_mfma(const unsigned short* __restrict__ qkv,
                                                  const unsigned short* __restrict__ Vt,
                                                  unsigned short* __restrict__ o)
{
    __shared__ unsigned short sK[64 * 64];
    __shared__ unsigned short sV[64 * 64];
    __shared__ unsigned short sP[8][16 * 64];
    const int t  = threadIdx.x;
    const int wv = t >> 6, ln = t & 63;
    const int lr = ln & 15, lg = ln >> 4;
    const int bh = blockIdx.y, b = bh >> 3, h = bh & 7;
    const int q0 = (blockIdx.x << 7) + (wv << 4);

    const unsigned short* qb = qkv + (long)b * SS * 1536 + h * DHH;
    const unsigned short* kb = qb + EE;
    const unsigned short* vt = Vt + (long)bh * DHH * SS;
    unsigned short* pw = sP[wv];

    const int srow = ln >> 3;
    const int ucol = ((ln & 7) ^ srow) << 3;

    bf16x8 aq[2];
    #pragma unroll
    for (int c = 0; c < 2; ++c)
        aq[c] = *(const bf16x8*)(qb + (long)(q0 + lr) * 1536 + (c << 5) + (lg << 3));

    float m_[4], l_[4];
    f32x4 accO[4];
    #pragma unroll
    for (int r = 0; r < 4; ++r) { m_[r] = -1e30f; l_[r] = 0.f; }
    #pragma unroll
    for (int n = 0; n < 4; ++n) accO[n] = (f32x4){0.f, 0.f, 0.f, 0.f};

    for (int s0 = 0; s0 < SS; s0 += 64) {
        __syncthreads();
        {
            const int row = (wv << 3) + srow;
            gload16(kb + (long)(s0 + row) * 1536 + ucol, (char*)sK + (wv << 10));
            gload16(vt + (long)row * SS + s0 + ucol,     (char*)sV + (wv << 10));
        }
        __syncthreads();

        f32x4 accS[4];
        #pragma unroll
        for (int sj = 0; sj < 4; ++sj) accS[sj] = (f32x4){0.f, 0.f, 0.f, 0.f};
        #pragma unroll
        for (int c = 0; c < 2; ++c) {
            const int slot = (c << 2) + lg;
            #pragma unroll
            for (int sj = 0; sj < 4; ++sj) {
                const int rw = (sj << 4) + lr;
                const bf16x8 kf = *(const bf16x8*)((const char*)sK + rw * 128 + ((slot ^ (rw & 7)) << 4));
                accS[sj] = __builtin_amdgcn_mfma_f32_16x16x32_bf16(aq[c], kf, accS[sj], 0, 0, 0);
            }
        }
        #pragma unroll
        for (int reg = 0; reg < 4; ++reg) {
            float sc0 = accS[0][reg] * 0.125f, sc1 = accS[1][reg] * 0.125f;
            float sc2 = accS[2][reg] * 0.125f, sc3 = accS[3][reg] * 0.125f;
            float mx = fmaxf(fmaxf(sc0, sc1), fmaxf(sc2, sc3));
            mx = fmaxf(mx, __shfl_xor(mx, 1));
            mx = fmaxf(mx, __shfl_xor(mx, 2));
            mx = fmaxf(mx, __shfl_xor(mx, 4));
            mx = fmaxf(mx, __shfl_xor(mx, 8));
            const float mnew = fmaxf(m_[reg], mx);
            const float f = __expf(m_[reg] - mnew);
            m_[reg] = mnew;
            sc0 = __expf(sc0 - mnew); sc1 = __expf(sc1 - mnew);
            sc2 = __expf(sc2 - mnew); sc3 = __expf(sc3 - mnew);
            accS[0][reg] = sc0; accS[1][reg] = sc1;
            accS[2][reg] = sc2; accS[3][reg] = sc3;
            float ss = sc0 + sc1 + sc2 + sc3;
            ss += __shfl_xor(ss, 1); ss += __shfl_xor(ss, 2);
            ss += __shfl_xor(ss, 4); ss += __shfl_xor(ss, 8);
            l_[reg] = l_[reg] * f + ss;
            #pragma unroll
            for (int n = 0; n < 4; ++n) accO[n][reg] *= f;
        }
        #pragma unroll
        for (int sj = 0; sj < 4; ++sj) {
            #pragma unroll
            for (int reg = 0; reg < 4; ++reg) {
                const int q = (lg << 2) + reg;
                const int s = (sj << 4) + lr;
                const int byte = (q << 7) + (((s >> 3) ^ (q & 7)) << 4) + ((s & 7) << 1);
                *(unsigned short*)((char*)pw + byte) = f2bf(accS[sj][reg]);
            }
        }
        #pragma unroll
        for (int c2 = 0; c2 < 2; ++c2) {
            const int pslot = ((c2 << 2) + lg) ^ (lr & 7);
            const bf16x8 pa = *(const bf16x8*)((const char*)pw + (lr << 7) + (pslot << 4));
            const int vslot = (c2 << 2) + lg;
            #pragma unroll
            for (int n = 0; n < 4; ++n) {
                const int rw = (n << 4) + lr;
                const bf16x8 vf = *(const bf16x8*)((const char*)sV + rw * 128 + ((vslot ^ (rw & 7)) << 4));
                accO[n] = __builtin_amdgcn_mfma_f32_16x16x32_bf16(pa, vf, accO[n], 0, 0, 0);
            }
        }
    }

    #pragma unroll
    for (int reg = 0; reg < 4; ++reg) {
        const float inv = 1.f / l_[reg];
        unsigned short* orow = o + (long)(b * SS + q0 + (lg << 2) + reg) * EE + h * DHH;
        #pragma unroll
        for (int n = 0; n < 4; ++n)
            orow[(n << 4) + lr] = f2bf(accO[n][reg] * inv);
    }
}

// ---------------------------------------------------------------------------
// Fused residual + LayerNorm, in place; also writes bf16 copy.
// ---------------------------------------------------------------------------
__global__ __launch_bounds__(256) void ln_fused(float* __restrict__ x,
                                                unsigned short* __restrict__ xb,
                                                const float* __restrict__ o,
                                                const float* __restrict__ g,
                                                const float* __restrict__ bta)
{
    const long row = blockIdx.x;
    float* xr = x + row * EE;
    unsigned short* hb = xb + row * EE;
    const float* orr = o + row * EE;
    const int t = threadIdx.x;
    const float v0 = xr[t] + orr[t];
    const float v1 = xr[t + 256] + orr[t + 256];
    float s = v0 + v1;
    #pragma unroll
    for (int off = 1; off < 64; off <<= 1) s += __shfl_xor(s, off);
    __shared__ float r1[4], r2[4];
    if ((t & 63) == 0) r1[t >> 6] = s;
    __syncthreads();
    const float mu = (r1[0] + r1[1] + r1[2] + r1[3]) * (1.f / EE);
    const float d0 = v0 - mu, d1 = v1 - mu;
    float q = d0 * d0 + d1 * d1;
    #pragma unroll
    for (int off = 1; off < 64; off <<= 1) q += __shfl_xor(q, off);
    if ((t & 63) == 0) r2[t >> 6] = q;
    __syncthreads();
    const float rs = rsqrtf((r2[0] + r2[1] + r2[2] + r2[3]) * (1.f / EE) + 1e-5f);
    const float y0 = d0 * rs * g[t]       + bta[t];
    const float y1 = d1 * rs * g[t + 256] + bta[t + 256];
    xr[t] = y0;  xr[t + 256] = y1;
    hb[t] = f2bf(y0);  hb[t + 256] = f2bf(y1);
}

// ---------------------------------------------------------------------------
extern "C" void kernel_launch(void* const* d_in, const int* in_sizes, int n_in,
                              void* d_out, int out_size, void* d_ws, size_t ws_size,
                              hipStream_t stream)
{
    const float* inp   = (const float*)d_in[0];
    const float* pe    = (const float*)d_in[1];
    const float* label = (const float*)d_in[2];
    const float* l1w   = (const float*)d_in[3];
    const float* l1b   = (const float*)d_in[4];
    const float* fcw   = (const float*)d_in[5];
    const float* fcb   = (const float*)d_in[6];
    const float* ipw   = (const float*)d_in[7];
    const float* ipb   = (const float*)d_in[8];
    const float* opw   = (const float*)d_in[9];
    const float* opb   = (const float*)d_in[10];
    const float* g1    = (const float*)d_in[11];
    const float* b1    = (const float*)d_in[12];
    const float* g2    = (const float*)d_in[13];
    const float* b2    = (const float*)d_in[14];
    const float* w1    = (const float*)d_in[15];
    const float* bb1   = (const float*)d_in[16];
    const float* w2    = (const float*)d_in[17];
    const float* bb2   = (const float*)d_in[18];

    // ---- workspace layout -------------------------------------------------
    char* wp = (char*)d_ws;
    float* x = (float*)wp;                 wp += (long)BB * SS * EE * 4;
    unsigned short* xb = (unsigned short*)wp;  wp += (long)BB * SS * EE * 2;
    float* bufo = (float*)wp;              wp += (long)BB * SS * EE * 4;
    unsigned short* big = (unsigned short*)wp; wp += (long)BB * SS * DFF_ * 2;
    unsigned short* ob  = (unsigned short*)wp; wp += (long)BB * SS * EE * 2;
    unsigned short* Vtb = (unsigned short*)wp; wp += (long)BB * HH * DHH * SS * 2;
    unsigned short* ipwb = (unsigned short*)wp; wp += (long)LLY * 3 * EE * EE * 2;
    unsigned short* opwb = (unsigned short*)wp; wp += (long)LLY * EE * EE * 2;
    unsigned short* w1b  = (unsigned short*)wp; wp += (long)LLY * DFF_ * EE * 2;
    unsigned short* w2b  = (unsigned short*)wp; wp += (long)LLY * EE * DFF_ * 2;
    unsigned short* l1wb = (unsigned short*)wp; wp += (long)EE * EE * 2;
    unsigned short* labelb = (unsigned short*)wp; wp += (long)CP * EE * 2;
    unsigned short* fcwb   = (unsigned short*)wp; wp += (long)CP * EE * 2;
    float2* stats   = (float2*)wp;         wp += (long)BB * CP * 16 * 8;
    float2* rowstat = (float2*)wp;         wp += (long)BB * CP * 8;
    unsigned short* rawb = (unsigned short*)wp;   // optional [B,CC,S] bf16
    const long raw_bytes = (long)BB * CC * SS * 2;
    const bool bf16raw = ((long)ws_size >= (wp - (char*)d_ws) + raw_bytes);

    float* out0  = (float*)d_out;
    float* attnW = out0 + BB * CC;

    {
        const long n1 = (long)LLY * 3 * EE * EE;
        cvt_bf16<<<(int)((n1 / 4 + 255) / 256), 256, 0, stream>>>(ipw, ipwb, n1, n1);
        const long n2 = (long)LLY * EE * EE;
        cvt_bf16<<<(int)((n2 / 4 + 255) / 256), 256, 0, stream>>>(opw, opwb, n2, n2);
        const long n3 = (long)LLY * DFF_ * EE;
        cvt_bf16<<<(int)((n3 / 4 + 255) / 256), 256, 0, stream>>>(w1, w1b, n3, n3);
        cvt_bf16<<<(int)((n3 / 4 + 255) / 256), 256, 0, stream>>>(w2, w2b, n3, n3);
        const long n4 = (long)EE * EE;
        cvt_bf16<<<(int)((n4 / 4 + 255) / 256), 256, 0, stream>>>(l1w, l1wb, n4, n4);
        const long n5i = (long)CC * EE, n5o = (long)CP * EE;
        cvt_bf16<<<(int)((n5o / 4 + 255) / 256), 256, 0, stream>>>(label, labelb, n5i, n5o);
        cvt_bf16<<<(int)((n5o / 4 + 255) / 256), 256, 0, stream>>>(fcw, fcwb, n5i, n5o);
    }

    const int M = BB * SS;   // 8192

    embed_kernel<<<4096, 256, 0, stream>>>(inp, pe, x, xb);

    for (int l = 0; l < LLY; ++l) {
        gemm_mfma_t<4><<<dim3(64, 12, 1), 256, 0, stream>>>(xb, ipwb + (long)l * 3 * EE * EE,
                                                            ipb + l * 3 * EE, nullptr, big,
                                                            M, 3 * EE, EE, M, 0, 0, 0, 0, 2);
        vtrans<<<dim3(16, 64), 256, 0, stream>>>(big, Vtb);
        flash_mfma<<<dim3(8, 64), 512, 0, stream>>>(big, Vtb, ob);
        gemm_mfma_t<2><<<dim3(64, 8, 1), 256, 0, stream>>>(ob, opwb + (long)l * EE * EE,
                                                           opb + l * EE, bufo, nullptr,
                                                           M, EE, EE, M, 0, 0, 0, 0, 1);
        ln_fused<<<M, 256, 0, stream>>>(x, xb, bufo, g1 + l * EE, b1 + l * EE);
        gemm_mfma_t<4><<<dim3(64, 16, 1), 256, 0, stream>>>(xb, w1b + (long)l * DFF_ * EE,
                                                            bb1 + l * DFF_, nullptr, big,
                                                            M, DFF_, EE, M, 0, 0, 0, 1, 2);
        gemm_mfma_t<2><<<dim3(64, 8, 1), 256, 0, stream>>>(big, w2b + (long)l * EE * DFF_,
                                                           bb2 + l * EE, bufo, nullptr,
                                                           M, EE, DFF_, M, 0, 0, 0, 0, 1);
        ln_fused<<<M, 256, 0, stream>>>(x, xb, bufo, g2 + l * EE, b2 + l * EE);
    }

    // o1 = tanh(x @ l1w^T + l1b) -> bf16 ob
    gemm_mfma_t<2><<<dim3(64, 8, 1), 256, 0, stream>>>(xb, l1wb, l1b, nullptr, ob,
                                                       M, EE, EE, M, 0, 0, 0, 2, 2);
    // raw scores + slice stats
    if (bf16raw)
        gemm_scores_t<true><<<dim3(CP / 128, SS / 128, BB), 256, 0, stream>>>(labelb, ob, attnW, rawb, stats);
    else
        gemm_scores_t<false><<<dim3(CP / 128, SS / 128, BB), 256, 0, stream>>>(labelb, ob, attnW, rawb, stats);
    // merge stats + init out = fc_b (fused)
    merge_stats<<<(int)(((long)BB * CP + 255) / 256), 256, 0, stream>>>(stats, rowstat, fcb, out0);
    // fused final: per-tile (r11 optimum), atomic combine, XCD-swizzled
    if (bf16raw)
        gemm_label_final_t<true><<<dim3(CP / 128, SS / 128, BB), 256, 0, stream>>>(fcwb, xb, attnW, rawb, rowstat, out0);
    else
        gemm_label_final_t<false><<<dim3(CP / 128, SS / 128, BB), 256, 0, stream>>>(fcwb, xb, attnW, rawb, rowstat, out0);
}